// Round 4
// baseline (275.336 us; speedup 1.0000x reference)
//
#include <hip/hip_runtime.h>
#include <hip/hip_fp16.h>

#define HH 256
#define WW 256
#define NB 64
#define NPIX (NB * HH * WW)      // 4,194,304 pixels
#define NF4  (NPIX / 4)          // 1,048,576 groups of 4
#define ROW4 (WW / 4)            // 64 groups per image row
#define EPSF 1e-12f
#define NTHR 256
#define NBLK (NF4 / NTHR)        // 4096 blocks (S kernel, flat)
#define FTRH 8                   // output rows per tile
#define FTHR 512                 // 8 waves
#define TPI  (HH / FTRH)         // 32 tiles per image
#define FBLK (NB * TPI)          // 2048 blocks (FP kernel)
#define NIT  3                   // solver iterations fused per FP launch
#define NU   (FTRH + 2 * NIT)        // 14 LDS u rows, rel [-3,10]
#define NPR  (FTRH + 2 * NIT - 1)    // 13 LDS p12/p22 rows, rel [-3,9]
// LDS = (14+13) rows * 1 KB = 27 KB. sPA eliminated (register-resident).

__device__ __forceinline__ float4 ld4(const float* p, int f) {
    return ((const float4*)p)[f];
}
__device__ __forceinline__ void st4(float* p, int f, const float* v) {
    ((float4*)p)[f] = make_float4(v[0], v[1], v[2], v[3]);
}
// Packed-pair load: 4 pixels of a __half2 field (16B) -> two float[4]
__device__ __forceinline__ void ld8h(const __half2* p, int f, float* a, float* b) {
    float4 raw = ((const float4*)p)[f];
    const __half2* h = (const __half2*)&raw;
    #pragma unroll
    for (int k = 0; k < 4; ++k) {
        float2 v = __half22float2(h[k]);
        a[k] = v.x; b[k] = v.y;
    }
}
__device__ __forceinline__ void st8h(__half2* p, int f, const float* a, const float* b) {
    float4 raw;
    __half2* h = (__half2*)&raw;
    #pragma unroll
    for (int k = 0; k < 4; ++k) h[k] = __floats2half2_rn(a[k], b[k]);
    ((float4*)p)[f] = raw;
}
// Pack 4 px of two fields into 4 __half2 inside a float4 (for LDS 16B store)
__device__ __forceinline__ float4 pack4h2(const float* a, const float* b) {
    float4 raw;
    __half2* h = (__half2*)&raw;
    #pragma unroll
    for (int k = 0; k < 4; ++k) h[k] = __floats2half2_rn(a[k], b[k]);
    return raw;
}
__device__ __forceinline__ void unpack4h2(float4 raw, float* a, float* b) {
    const __half2* h = (const __half2*)&raw;
    #pragma unroll
    for (int k = 0; k < 4; ++k) {
        float2 v = __half22float2(h[k]);
        a[k] = v.x; b[k] = v.y;
    }
}

// TV-L1 thresholding step, branch-free:
//   v = med3(-rho/grad, -l_t, l_t) * g   — agrees exactly with the 3-mask
// reference logic. grad >= EPSF so rcp is safe.
__device__ __forceinline__ void thresh(
    float gx, float gy, float rho, float grad, float l_t,
    float& v1, float& v2)
{
    float s = -rho * __builtin_amdgcn_rcpf(grad);
    float c = __builtin_amdgcn_fmed3f(s, -l_t, l_t);
    v1 = c * gx; v2 = c * gy;
}

// p-pair update at one pixel for one flow (approx sqrt/rcp: err ~2^-22,
// far below the fp16 quantization the state pays at block boundaries).
__device__ __forceinline__ void pupd(
    float pao, float pbo, float ux, float uy, float taut,
    float& pa, float& pb)
{
    float n2 = fmaf(ux, ux, fmaf(uy, uy, EPSF));
    float n  = __builtin_amdgcn_sqrtf(n2);
    float r  = __builtin_amdgcn_rcpf(fmaf(taut, n, 1.f));
    pa = fmaf(taut, ux, pao) * r;
    pb = fmaf(taut, uy, pbo) * r;
}

// ---------------------------------------------------------------------------
// S: packed g=(gx,gy) fp16x2 and rc fp32 from x,y. Each wave covers one full
// image row: column neighbors come via shuffles.
// ---------------------------------------------------------------------------
__global__ __launch_bounds__(NTHR) void s_kernel(
    const float* __restrict__ x, const float* __restrict__ y,
    __half2* __restrict__ ga, float* __restrict__ rc)
{
    int f = blockIdx.x * NTHR + threadIdx.x;
    int idx = f << 2;
    int i  = (idx >> 8) & 255;

    float4 xc4 = ld4(x, f), yc4 = ld4(y, f);
    const float* xc = (const float*)&xc4;
    const float* yc = (const float*)&yc4;

    float4 a4, b4;                       // wave-uniform row branch
    if (i == 0)            { a4 = ld4(x, f + ROW4); b4 = xc4; }
    else if (i == HH - 1)  { a4 = xc4; b4 = ld4(x, f - ROW4); }
    else                   { a4 = ld4(y, f + ROW4); b4 = ld4(y, f - ROW4); }
    const float* aa = (const float*)&a4;
    const float* bb = (const float*)&b4;

    // column neighbors from adjacent lanes (wave spans the full row)
    float yl = __shfl_up(yc4.w, 1);      // y[idx-1]; lane 0 value unused
    float yr = __shfl_down(yc4.x, 1);    // y[idx+4]; lane 63 value unused

    int j0 = idx & 255;
    float gxo[4], gyo[4], rco[4];
    #pragma unroll
    for (int k = 0; k < 4; ++k) {
        int j = j0 + k;
        float gx;
        if (j == 0)            gx = 0.5f * (xc[1] - xc[0]);
        else if (j == WW - 1)  gx = 0.5f * (xc[3] - xc[2]);
        else {
            float ynext = (k < 3) ? yc[k + 1] : yr;
            float yprev = (k > 0) ? yc[k - 1] : yl;
            gx = 0.5f * (ynext - yprev);
        }
        float gy = 0.5f * (aa[k] - bb[k]);
        gxo[k] = gx; gyo[k] = gy;        // st8h rounds to fp16 (rn) on store
        rco[k] = yc[k] - xc[k];
    }
    st8h(ga, f, gxo, gyo); st4(rc, f, rco);
}

// ---------------------------------------------------------------------------
// FP: 3 fused solver iterations, FIXED row ownership + register-resident
// state. Wave tr owns rel rows {tr-3, tr+5} for the whole kernel; u and all
// four p fields stay in fp32 registers across iterations. Cross-wave flows
// only: sU (down-row u, read in p-step) and sPB = (p12,p22) (up-row p, read
// in u-step). Left/right pixel neighbors travel by lane shuffle of registers.
// P0: p(k-1)=0 and u(k)=thresh(ga,rc) in-register. LAST: fp32 u out.
// ---------------------------------------------------------------------------
template <bool P0, bool LAST>
__global__ __launch_bounds__(FTHR, 6) void fp_kernel(
    const __half2* __restrict__ ga, const float* __restrict__ rc,
    const __half2* __restrict__ upi,
    const __half2* __restrict__ pai, const __half2* __restrict__ pbi,
    __half2* __restrict__ upo,
    float* __restrict__ u1f, float* __restrict__ u2f,
    __half2* __restrict__ pao, __half2* __restrict__ pbo,
    const float* __restrict__ tp, const float* __restrict__ lp,
    const float* __restrict__ ap)
{
    __shared__ alignas(16) __half2 sU [NU ][WW];   // (u1,u2),  rel rows [-3,10]
    __shared__ alignas(16) __half2 sPB[NPR][WW];   // (p12,p22), rel rows [-3,9]

    const float ts   = tp[0];
    const float l_t  = lp[0] * ts;
    const float taut = ap[0] / ts;

    const int t     = threadIdx.x;
    const int tile  = blockIdx.x;
    const int i0    = (tile & (TPI - 1)) * FTRH;   // tile top row
    const int base4 = (tile / TPI) * (HH * ROW4);  // batch offset, float4 units

    const int tr  = t >> 6;       // wave index 0..7
    const int tcg = t & 63;       // lane
    const int tc  = tcg * 4;

    // persistent per-thread state for the 2 owned rows
    float u1[2][4], u2[2][4];
    float p11[2][4], p12[2][4], p21[2][4], p22[2][4];

    // ---- prologue: load u(k) + p(k-1) into regs; seed sU ----
    #pragma unroll
    for (int s = 0; s < 2; ++s) {
        const int rr = tr - NIT + 8 * s;   // owned rel row: -3..4 / 5..12
        const int gr = i0 + rr;
        const int li = rr + NIT;
        if (gr >= 0 && gr < HH) {
            const int f = base4 + gr * ROW4 + tcg;
            if (P0) {
                float gx[4], gy[4];
                ld8h(ga, f, gx, gy);
                float4 rc4 = ld4(rc, f);
                const float* rcv = (const float*)&rc4;
                #pragma unroll
                for (int k = 0; k < 4; ++k) {
                    float grad = fmaf(gx[k], gx[k], fmaf(gy[k], gy[k], EPSF));
                    thresh(gx[k], gy[k], rcv[k] + EPSF, grad, l_t,
                           u1[s][k], u2[s][k]);            // u(1), div(p0)=0
                }
            } else {
                ld8h(upi, f, u1[s], u2[s]);
            }
            if (!P0 && rr <= FTRH + 1) {   // rows <= 9 can be p-active
                ld8h(pai, f, p11[s], p12[s]);
                ld8h(pbi, f, p21[s], p22[s]);
            } else {
                #pragma unroll
                for (int k = 0; k < 4; ++k)
                    { p11[s][k]=p12[s][k]=p21[s][k]=p22[s][k]=0.f; }
            }
        } else {
            #pragma unroll
            for (int k = 0; k < 4; ++k) {
                u1[s][k]=u2[s][k]=0.f;
                p11[s][k]=p12[s][k]=p21[s][k]=p22[s][k]=0.f;
            }
        }
        if (li < NU) *(float4*)&sU[li][tc] = pack4h2(u1[s], u2[s]);
    }
    __syncthreads();

    #pragma unroll
    for (int m = 0; m < NIT; ++m) {
        const int plo = -(NIT - m);
        const int phi = FTRH - 1 + (NIT - 1 - m);

        // ===== p-step m: rows [plo, phi], in-place on register p =====
        #pragma unroll
        for (int s = 0; s < 2; ++s) {
            const int rr = tr - NIT + 8 * s;
            if (rr < plo || rr > phi) continue;        // wave-uniform
            const int gr = i0 + rr;
            const int li = rr + NIT;
            if (gr >= 0 && gr < HH) {
                const bool hasDn = (gr < HH - 1);
                float u1d[4] = {0,0,0,0}, u2d[4] = {0,0,0,0};
                if (hasDn) unpack4h2(*(const float4*)&sU[li + 1][tc], u1d, u2d);
                const float u1r = __shfl_down(u1[s][0], 1);   // lane+1 px
                const float u2r = __shfl_down(u2[s][0], 1);
                #pragma unroll
                for (int k = 0; k < 4; ++k) {
                    const int j = tc + k;
                    float du1 = (k < 3) ? u1[s][k + 1] : u1r;
                    float du2 = (k < 3) ? u2[s][k + 1] : u2r;
                    float u1x = (j < WW - 1) ? du1 - u1[s][k] : 0.f;
                    float u2x = (j < WW - 1) ? du2 - u2[s][k] : 0.f;
                    float u1y = hasDn ? u1d[k] - u1[s][k] : 0.f;
                    float u2y = hasDn ? u2d[k] - u2[s][k] : 0.f;
                    pupd(p11[s][k], p12[s][k], u1x, u1y, taut,
                         p11[s][k], p12[s][k]);
                    pupd(p21[s][k], p22[s][k], u2x, u2y, taut,
                         p21[s][k], p22[s][k]);
                }
                *(float4*)&sPB[li][tc] = pack4h2(p12[s], p22[s]);
                if (m == NIT - 1 && !LAST && rr >= 0 && rr < FTRH) {
                    const int f = base4 + gr * ROW4 + tcg;
                    st8h(pao, f, p11[s], p12[s]);
                    st8h(pbo, f, p21[s], p22[s]);
                }
            } else {
                *(float4*)&sPB[li][tc] = make_float4(0.f, 0.f, 0.f, 0.f);
            }
        }
        __syncthreads();

        // ===== u-step m: rows [plo+1, phi], in-place on register u =====
        const int ulo = plo + 1, uhi = phi;
        #pragma unroll
        for (int s = 0; s < 2; ++s) {
            const int rr = tr - NIT + 8 * s;
            if (rr < ulo || rr > uhi) continue;        // wave-uniform
            const int gr = i0 + rr;
            if (gr < 0 || gr >= HH) continue;          // wave-uniform
            const int li = rr + NIT;
            const int f  = base4 + gr * ROW4 + tcg;
            float gx[4], gy[4];
            ld8h(ga, f, gx, gy);                       // halo re-reads hit L1/L2
            float4 rc4 = ld4(rc, f);
            const float* rcv = (const float*)&rc4;
            float q12[4], q22[4];
            unpack4h2(*(const float4*)&sPB[li - 1][tc], q12, q22);  // up-row p
            float l11 = __shfl_up(p11[s][3], 1);       // lane-1 px, own row
            float l21 = __shfl_up(p21[s][3], 1);
            if (tcg == 0) { l11 = 0.f; l21 = 0.f; }    // j==0 boundary
            const bool hasDn = (gr < HH - 1);
            #pragma unroll
            for (int k = 0; k < 4; ++k) {
                const int j = tc + k;
                float t11  = (j < WW - 1) ? p11[s][k] : 0.f;
                float t21  = (j < WW - 1) ? p21[s][k] : 0.f;
                float l11k = (k == 0) ? l11 : p11[s][k - 1];
                float l21k = (k == 0) ? l21 : p21[s][k - 1];
                float t12  = hasDn ? p12[s][k] : 0.f;
                float t22  = hasDn ? p22[s][k] : 0.f;
                float div1 = (t11 - l11k) + (t12 - q12[k]);
                float div2 = (t21 - l21k) + (t22 - q22[k]);

                float grad = fmaf(gx[k], gx[k], fmaf(gy[k], gy[k], EPSF));
                float rho  = rcv[k] + gx[k]*u1[s][k] + gy[k]*u2[s][k] + EPSF;
                float v1, v2;
                thresh(gx[k], gy[k], rho, grad, l_t, v1, v2);
                u1[s][k] = v1 + u1[s][k] + ts * div1;
                u2[s][k] = v2 + u2[s][k] + ts * div2;
            }
            if (m == NIT - 1) {
                if (LAST) { st4(u1f, f, u1[s]); st4(u2f, f, u2[s]); }
                else      { st8h(upo, f, u1[s], u2[s]); }
            } else {
                *(float4*)&sU[li][tc] = pack4h2(u1[s], u2[s]);
            }
        }
        if (m < NIT - 1) __syncthreads();
    }
}

// ---------------------------------------------------------------------------
extern "C" void kernel_launch(void* const* d_in, const int* in_sizes, int n_in,
                              void* d_out, int out_size, void* d_ws, size_t ws_size,
                              hipStream_t stream) {
    const float* x = (const float*)d_in[0];
    const float* y = (const float*)d_in[1];
    const float* t = (const float*)d_in[8];
    const float* l = (const float*)d_in[9];
    const float* a = (const float*)d_in[10];

    float* u1out = (float*)d_out;
    float* u2out = u1out + NPIX;

    // ws: rc(f32) + 7 packed half2 fields = 8 * 16.8 MB = 134 MB
    char* ws = (char*)d_ws;
    float*   rcp_ = (float*)ws;                              ws += (size_t)NPIX * 4;
    __half2* gaP  = (__half2*)ws;                            ws += (size_t)NPIX * 4;
    __half2* upA  = (__half2*)ws;                            ws += (size_t)NPIX * 4;
    __half2* upB  = (__half2*)ws;                            ws += (size_t)NPIX * 4;
    __half2* paA  = (__half2*)ws;                            ws += (size_t)NPIX * 4;
    __half2* pbA  = (__half2*)ws;                            ws += (size_t)NPIX * 4;
    __half2* paB  = (__half2*)ws;                            ws += (size_t)NPIX * 4;
    __half2* pbB  = (__half2*)ws;

    // S: ga, rc only (u(1) recomputed in FP1)
    s_kernel<<<dim3(NBLK), dim3(NTHR), 0, stream>>>(x, y, gaP, rcp_);

    // FP1: iterations 1-3  (p1..p3, u2..u4), p0 = 0, u1 in-register
    fp_kernel<true, false><<<dim3(FBLK), dim3(FTHR), 0, stream>>>(
        gaP, rcp_, nullptr, nullptr, nullptr,
        upA, nullptr, nullptr, paA, pbA, t, l, a);

    // FP2: iterations 4-6  (p4..p6, u5..u7)
    fp_kernel<false, false><<<dim3(FBLK), dim3(FTHR), 0, stream>>>(
        gaP, rcp_, upA, paA, pbA,
        upB, nullptr, nullptr, paB, pbB, t, l, a);

    // FP3: iterations 7-9 + final u(10) as fp32; dead p(9) store skipped
    fp_kernel<false, true><<<dim3(FBLK), dim3(FTHR), 0, stream>>>(
        gaP, rcp_, upB, paB, pbB,
        nullptr, u1out, u2out, nullptr, nullptr, t, l, a);
}

// Round 5
// 235.717 us; speedup vs baseline: 1.1681x; 1.1681x over previous
//
#include <hip/hip_runtime.h>
#include <hip/hip_fp16.h>

#define HH 256
#define WW 256
#define NB 64
#define NPIX (NB * HH * WW)      // 4,194,304 pixels
#define NF4  (NPIX / 4)          // 1,048,576 groups of 4
#define ROW4 (WW / 4)            // 64 groups per image row
#define EPSF 1e-12f
#define NTHR 256
#define NBLK (NF4 / NTHR)        // 4096 blocks (S kernel, flat)
#define FTRH 8                   // output rows per tile
#define FTHR 512                 // 8 waves
#define TPI  (HH / FTRH)         // 32 tiles per image
#define FBLK (NB * TPI)          // 2048 blocks (FP kernel)
#define NIT  3                   // solver iterations fused per FP launch
#define NU   (FTRH + 2 * NIT)        // 14 LDS u rows, rel [-3,10]
#define NPR  (FTRH + 2 * NIT - 1)    // 13 LDS p12/p22 rows, rel [-3,9]
// LDS = (14+13) rows * 1 KB = 27 KB. sPA eliminated (register-resident).
// __launch_bounds__(512,4): VGPR cap 128 so the ~90-reg state does NOT
// spill (round-4 lesson: (512,6) forced the 64-VGPR bucket -> scratch).

__device__ __forceinline__ float4 ld4(const float* p, int f) {
    return ((const float4*)p)[f];
}
__device__ __forceinline__ void st4(float* p, int f, const float* v) {
    ((float4*)p)[f] = make_float4(v[0], v[1], v[2], v[3]);
}
// Packed-pair load: 4 pixels of a __half2 field (16B) -> two float[4]
__device__ __forceinline__ void ld8h(const __half2* p, int f, float* a, float* b) {
    float4 raw = ((const float4*)p)[f];
    const __half2* h = (const __half2*)&raw;
    #pragma unroll
    for (int k = 0; k < 4; ++k) {
        float2 v = __half22float2(h[k]);
        a[k] = v.x; b[k] = v.y;
    }
}
__device__ __forceinline__ void st8h(__half2* p, int f, const float* a, const float* b) {
    float4 raw;
    __half2* h = (__half2*)&raw;
    #pragma unroll
    for (int k = 0; k < 4; ++k) h[k] = __floats2half2_rn(a[k], b[k]);
    ((float4*)p)[f] = raw;
}
// Pack 4 px of two fields into 4 __half2 inside a float4 (for LDS 16B store)
__device__ __forceinline__ float4 pack4h2(const float* a, const float* b) {
    float4 raw;
    __half2* h = (__half2*)&raw;
    #pragma unroll
    for (int k = 0; k < 4; ++k) h[k] = __floats2half2_rn(a[k], b[k]);
    return raw;
}
__device__ __forceinline__ void unpack4h2(float4 raw, float* a, float* b) {
    const __half2* h = (const __half2*)&raw;
    #pragma unroll
    for (int k = 0; k < 4; ++k) {
        float2 v = __half22float2(h[k]);
        a[k] = v.x; b[k] = v.y;
    }
}

// TV-L1 thresholding step, branch-free:
//   v = med3(-rho/grad, -l_t, l_t) * g   — agrees exactly with the 3-mask
// reference logic. grad >= EPSF so rcp is safe.
__device__ __forceinline__ void thresh(
    float gx, float gy, float rho, float grad, float l_t,
    float& v1, float& v2)
{
    float s = -rho * __builtin_amdgcn_rcpf(grad);
    float c = __builtin_amdgcn_fmed3f(s, -l_t, l_t);
    v1 = c * gx; v2 = c * gy;
}

// p-pair update at one pixel for one flow (approx sqrt/rcp: err ~2^-22,
// far below the fp16 quantization the state pays at block boundaries).
__device__ __forceinline__ void pupd(
    float pao, float pbo, float ux, float uy, float taut,
    float& pa, float& pb)
{
    float n2 = fmaf(ux, ux, fmaf(uy, uy, EPSF));
    float n  = __builtin_amdgcn_sqrtf(n2);
    float r  = __builtin_amdgcn_rcpf(fmaf(taut, n, 1.f));
    pa = fmaf(taut, ux, pao) * r;
    pb = fmaf(taut, uy, pbo) * r;
}

// ---------------------------------------------------------------------------
// S: packed g=(gx,gy) fp16x2 and rc fp32 from x,y. Each wave covers one full
// image row: column neighbors come via shuffles.
// ---------------------------------------------------------------------------
__global__ __launch_bounds__(NTHR) void s_kernel(
    const float* __restrict__ x, const float* __restrict__ y,
    __half2* __restrict__ ga, float* __restrict__ rc)
{
    int f = blockIdx.x * NTHR + threadIdx.x;
    int idx = f << 2;
    int i  = (idx >> 8) & 255;

    float4 xc4 = ld4(x, f), yc4 = ld4(y, f);
    const float* xc = (const float*)&xc4;
    const float* yc = (const float*)&yc4;

    float4 a4, b4;                       // wave-uniform row branch
    if (i == 0)            { a4 = ld4(x, f + ROW4); b4 = xc4; }
    else if (i == HH - 1)  { a4 = xc4; b4 = ld4(x, f - ROW4); }
    else                   { a4 = ld4(y, f + ROW4); b4 = ld4(y, f - ROW4); }
    const float* aa = (const float*)&a4;
    const float* bb = (const float*)&b4;

    // column neighbors from adjacent lanes (wave spans the full row)
    float yl = __shfl_up(yc4.w, 1);      // y[idx-1]; lane 0 value unused
    float yr = __shfl_down(yc4.x, 1);    // y[idx+4]; lane 63 value unused

    int j0 = idx & 255;
    float gxo[4], gyo[4], rco[4];
    #pragma unroll
    for (int k = 0; k < 4; ++k) {
        int j = j0 + k;
        float gx;
        if (j == 0)            gx = 0.5f * (xc[1] - xc[0]);
        else if (j == WW - 1)  gx = 0.5f * (xc[3] - xc[2]);
        else {
            float ynext = (k < 3) ? yc[k + 1] : yr;
            float yprev = (k > 0) ? yc[k - 1] : yl;
            gx = 0.5f * (ynext - yprev);
        }
        float gy = 0.5f * (aa[k] - bb[k]);
        gxo[k] = gx; gyo[k] = gy;        // st8h rounds to fp16 (rn) on store
        rco[k] = yc[k] - xc[k];
    }
    st8h(ga, f, gxo, gyo); st4(rc, f, rco);
}

// ---------------------------------------------------------------------------
// FP: 3 fused solver iterations, FIXED row ownership + register-resident
// state. Wave tr owns rel rows {tr-3, tr+5} for the whole kernel; u and all
// four p fields stay in fp32 registers across iterations. Cross-wave flows
// only: sU (down-row u, read in p-step) and sPB = (p12,p22) (up-row p, read
// in u-step). Left/right pixel neighbors travel by lane shuffle of registers.
// Rel rows 11-12 are dead (p-active<=9, u-active<=9, sU<=10): not loaded.
// P0: p(k-1)=0 and u(k)=thresh(ga,rc) in-register. LAST: fp32 u out.
// ---------------------------------------------------------------------------
template <bool P0, bool LAST>
__global__ __launch_bounds__(FTHR, 4) void fp_kernel(
    const __half2* __restrict__ ga, const float* __restrict__ rc,
    const __half2* __restrict__ upi,
    const __half2* __restrict__ pai, const __half2* __restrict__ pbi,
    __half2* __restrict__ upo,
    float* __restrict__ u1f, float* __restrict__ u2f,
    __half2* __restrict__ pao, __half2* __restrict__ pbo,
    const float* __restrict__ tp, const float* __restrict__ lp,
    const float* __restrict__ ap)
{
    __shared__ alignas(16) __half2 sU [NU ][WW];   // (u1,u2),  rel rows [-3,10]
    __shared__ alignas(16) __half2 sPB[NPR][WW];   // (p12,p22), rel rows [-3,9]

    const float ts   = tp[0];
    const float l_t  = lp[0] * ts;
    const float taut = ap[0] / ts;

    const int t     = threadIdx.x;
    const int tile  = blockIdx.x;
    const int i0    = (tile & (TPI - 1)) * FTRH;   // tile top row
    const int base4 = (tile / TPI) * (HH * ROW4);  // batch offset, float4 units

    const int tr  = t >> 6;       // wave index 0..7
    const int tcg = t & 63;       // lane
    const int tc  = tcg * 4;

    // persistent per-thread state for the 2 owned rows
    float u1[2][4], u2[2][4];
    float p11[2][4], p12[2][4], p21[2][4], p22[2][4];

    // ---- prologue: load u(k) + p(k-1) into regs; seed sU ----
    #pragma unroll
    for (int s = 0; s < 2; ++s) {
        const int rr = tr - NIT + 8 * s;   // owned rel row: -3..4 / 5..12
        const int gr = i0 + rr;
        const int li = rr + NIT;
        #pragma unroll
        for (int k = 0; k < 4; ++k) {
            u1[s][k]=u2[s][k]=0.f;
            p11[s][k]=p12[s][k]=p21[s][k]=p22[s][k]=0.f;
        }
        // rows > 10 are never consumed: skip their loads entirely
        if (gr >= 0 && gr < HH && rr <= FTRH + 2) {
            const int f = base4 + gr * ROW4 + tcg;
            if (P0) {
                float gx[4], gy[4];
                ld8h(ga, f, gx, gy);
                float4 rc4 = ld4(rc, f);
                const float* rcv = (const float*)&rc4;
                #pragma unroll
                for (int k = 0; k < 4; ++k) {
                    float grad = fmaf(gx[k], gx[k], fmaf(gy[k], gy[k], EPSF));
                    thresh(gx[k], gy[k], rcv[k] + EPSF, grad, l_t,
                           u1[s][k], u2[s][k]);            // u(1), div(p0)=0
                }
            } else {
                ld8h(upi, f, u1[s], u2[s]);
            }
            if (!P0 && rr <= FTRH + 1) {   // rows <= 9 can be p-active
                ld8h(pai, f, p11[s], p12[s]);
                ld8h(pbi, f, p21[s], p22[s]);
            }
        }
        if (li < NU) *(float4*)&sU[li][tc] = pack4h2(u1[s], u2[s]);
    }
    __syncthreads();

    #pragma unroll
    for (int m = 0; m < NIT; ++m) {
        const int plo = -(NIT - m);
        const int phi = FTRH - 1 + (NIT - 1 - m);

        // ===== p-step m: rows [plo, phi], in-place on register p =====
        #pragma unroll
        for (int s = 0; s < 2; ++s) {
            const int rr = tr - NIT + 8 * s;
            if (rr < plo || rr > phi) continue;        // wave-uniform
            const int gr = i0 + rr;
            const int li = rr + NIT;
            if (gr >= 0 && gr < HH) {
                const bool hasDn = (gr < HH - 1);
                float u1d[4] = {0,0,0,0}, u2d[4] = {0,0,0,0};
                if (hasDn) unpack4h2(*(const float4*)&sU[li + 1][tc], u1d, u2d);
                const float u1r = __shfl_down(u1[s][0], 1);   // lane+1 px
                const float u2r = __shfl_down(u2[s][0], 1);
                #pragma unroll
                for (int k = 0; k < 4; ++k) {
                    const int j = tc + k;
                    float du1 = (k < 3) ? u1[s][k + 1] : u1r;
                    float du2 = (k < 3) ? u2[s][k + 1] : u2r;
                    float u1x = (j < WW - 1) ? du1 - u1[s][k] : 0.f;
                    float u2x = (j < WW - 1) ? du2 - u2[s][k] : 0.f;
                    float u1y = hasDn ? u1d[k] - u1[s][k] : 0.f;
                    float u2y = hasDn ? u2d[k] - u2[s][k] : 0.f;
                    pupd(p11[s][k], p12[s][k], u1x, u1y, taut,
                         p11[s][k], p12[s][k]);
                    pupd(p21[s][k], p22[s][k], u2x, u2y, taut,
                         p21[s][k], p22[s][k]);
                }
                *(float4*)&sPB[li][tc] = pack4h2(p12[s], p22[s]);
                if (m == NIT - 1 && !LAST && rr >= 0 && rr < FTRH) {
                    const int f = base4 + gr * ROW4 + tcg;
                    st8h(pao, f, p11[s], p12[s]);
                    st8h(pbo, f, p21[s], p22[s]);
                }
            } else {
                *(float4*)&sPB[li][tc] = make_float4(0.f, 0.f, 0.f, 0.f);
            }
        }
        __syncthreads();

        // ===== u-step m: rows [plo+1, phi], in-place on register u =====
        const int ulo = plo + 1, uhi = phi;
        #pragma unroll
        for (int s = 0; s < 2; ++s) {
            const int rr = tr - NIT + 8 * s;
            if (rr < ulo || rr > uhi) continue;        // wave-uniform
            const int gr = i0 + rr;
            if (gr < 0 || gr >= HH) continue;          // wave-uniform
            const int li = rr + NIT;
            const int f  = base4 + gr * ROW4 + tcg;
            float gx[4], gy[4];
            ld8h(ga, f, gx, gy);                       // halo re-reads hit L1/L2
            float4 rc4 = ld4(rc, f);
            const float* rcv = (const float*)&rc4;
            float q12[4], q22[4];
            unpack4h2(*(const float4*)&sPB[li - 1][tc], q12, q22);  // up-row p
            float l11 = __shfl_up(p11[s][3], 1);       // lane-1 px, own row
            float l21 = __shfl_up(p21[s][3], 1);
            if (tcg == 0) { l11 = 0.f; l21 = 0.f; }    // j==0 boundary
            const bool hasDn = (gr < HH - 1);
            #pragma unroll
            for (int k = 0; k < 4; ++k) {
                const int j = tc + k;
                float t11  = (j < WW - 1) ? p11[s][k] : 0.f;
                float t21  = (j < WW - 1) ? p21[s][k] : 0.f;
                float l11k = (k == 0) ? l11 : p11[s][k - 1];
                float l21k = (k == 0) ? l21 : p21[s][k - 1];
                float t12  = hasDn ? p12[s][k] : 0.f;
                float t22  = hasDn ? p22[s][k] : 0.f;
                float div1 = (t11 - l11k) + (t12 - q12[k]);
                float div2 = (t21 - l21k) + (t22 - q22[k]);

                float grad = fmaf(gx[k], gx[k], fmaf(gy[k], gy[k], EPSF));
                float rho  = rcv[k] + gx[k]*u1[s][k] + gy[k]*u2[s][k] + EPSF;
                float v1, v2;
                thresh(gx[k], gy[k], rho, grad, l_t, v1, v2);
                u1[s][k] = v1 + u1[s][k] + ts * div1;
                u2[s][k] = v2 + u2[s][k] + ts * div2;
            }
            if (m == NIT - 1) {
                if (LAST) { st4(u1f, f, u1[s]); st4(u2f, f, u2[s]); }
                else      { st8h(upo, f, u1[s], u2[s]); }
            } else {
                *(float4*)&sU[li][tc] = pack4h2(u1[s], u2[s]);
            }
        }
        if (m < NIT - 1) __syncthreads();
    }
}

// ---------------------------------------------------------------------------
extern "C" void kernel_launch(void* const* d_in, const int* in_sizes, int n_in,
                              void* d_out, int out_size, void* d_ws, size_t ws_size,
                              hipStream_t stream) {
    const float* x = (const float*)d_in[0];
    const float* y = (const float*)d_in[1];
    const float* t = (const float*)d_in[8];
    const float* l = (const float*)d_in[9];
    const float* a = (const float*)d_in[10];

    float* u1out = (float*)d_out;
    float* u2out = u1out + NPIX;

    // ws: rc(f32) + 7 packed half2 fields = 8 * 16.8 MB = 134 MB
    char* ws = (char*)d_ws;
    float*   rcp_ = (float*)ws;                              ws += (size_t)NPIX * 4;
    __half2* gaP  = (__half2*)ws;                            ws += (size_t)NPIX * 4;
    __half2* upA  = (__half2*)ws;                            ws += (size_t)NPIX * 4;
    __half2* upB  = (__half2*)ws;                            ws += (size_t)NPIX * 4;
    __half2* paA  = (__half2*)ws;                            ws += (size_t)NPIX * 4;
    __half2* pbA  = (__half2*)ws;                            ws += (size_t)NPIX * 4;
    __half2* paB  = (__half2*)ws;                            ws += (size_t)NPIX * 4;
    __half2* pbB  = (__half2*)ws;

    // S: ga, rc only (u(1) recomputed in FP1)
    s_kernel<<<dim3(NBLK), dim3(NTHR), 0, stream>>>(x, y, gaP, rcp_);

    // FP1: iterations 1-3  (p1..p3, u2..u4), p0 = 0, u1 in-register
    fp_kernel<true, false><<<dim3(FBLK), dim3(FTHR), 0, stream>>>(
        gaP, rcp_, nullptr, nullptr, nullptr,
        upA, nullptr, nullptr, paA, pbA, t, l, a);

    // FP2: iterations 4-6  (p4..p6, u5..u7)
    fp_kernel<false, false><<<dim3(FBLK), dim3(FTHR), 0, stream>>>(
        gaP, rcp_, upA, paA, pbA,
        upB, nullptr, nullptr, paB, pbB, t, l, a);

    // FP3: iterations 7-9 + final u(10) as fp32; dead p(9) store skipped
    fp_kernel<false, true><<<dim3(FBLK), dim3(FTHR), 0, stream>>>(
        gaP, rcp_, upB, paB, pbB,
        nullptr, u1out, u2out, nullptr, nullptr, t, l, a);
}

// Round 6
// 232.016 us; speedup vs baseline: 1.1867x; 1.0160x over previous
//
#include <hip/hip_runtime.h>
#include <hip/hip_fp16.h>

#define HH 256
#define WW 256
#define NB 64
#define NPIX (NB * HH * WW)      // 4,194,304 pixels
#define NF4  (NPIX / 4)          // 1,048,576 groups of 4
#define ROW4 (WW / 4)            // 64 groups per image row
#define EPSF 1e-12f
#define NTHR 256
#define NBLK (NF4 / NTHR)        // 4096 blocks (S kernel, flat)
#define FTRH 8                   // output rows per tile
#define FTHR 512                 // 8 waves
#define TPI  (HH / FTRH)         // 32 tiles per image
#define FBLK (NB * TPI)          // 2048 blocks (FP kernel)
#define NIT  3                   // solver iterations fused per FP launch
#define NU   (FTRH + 2 * NIT)        // 14 LDS u rows, rel [-3,10]
#define NPR  (FTRH + 2 * NIT - 1)    // 13 LDS p12/p22 rows, rel [-3,9]
// LDS: fp32 planes sU1,sU2 (14 rows) + sP12,sP22 (13 rows) = 55.3 KB ->
// 2 blocks/CU. fp32 LDS deletes all pack/unpack cvt in the steady state;
// 16 B/lane contiguous access keeps the 0-bank-conflict pattern.
// __launch_bounds__(512,4): VGPR cap 128; persistent state ~72 floats
// (u 16, p 32, ga 16, rc 8) + temps fits without spill/AGPR-shuttling.

__device__ __forceinline__ float4 ld4(const float* p, int f) {
    return ((const float4*)p)[f];
}
__device__ __forceinline__ void st4(float* p, int f, const float* v) {
    ((float4*)p)[f] = make_float4(v[0], v[1], v[2], v[3]);
}
// Packed-pair load: 4 pixels of a __half2 field (16B) -> two float[4]
__device__ __forceinline__ void ld8h(const __half2* p, int f, float* a, float* b) {
    float4 raw = ((const float4*)p)[f];
    const __half2* h = (const __half2*)&raw;
    #pragma unroll
    for (int k = 0; k < 4; ++k) {
        float2 v = __half22float2(h[k]);
        a[k] = v.x; b[k] = v.y;
    }
}
__device__ __forceinline__ void st8h(__half2* p, int f, const float* a, const float* b) {
    float4 raw;
    __half2* h = (__half2*)&raw;
    #pragma unroll
    for (int k = 0; k < 4; ++k) h[k] = __floats2half2_rn(a[k], b[k]);
    ((float4*)p)[f] = raw;
}
__device__ __forceinline__ void st8h_dual(__half2* p, int f, const float* a, const float* b) {
    st8h(p, f, a, b);
}
// float[4] <-> float4 helpers for fp32 LDS planes
__device__ __forceinline__ void ldp4(const float* lds, float* v) {
    float4 r = *(const float4*)lds;
    v[0] = r.x; v[1] = r.y; v[2] = r.z; v[3] = r.w;
}
__device__ __forceinline__ void stp4(float* lds, const float* v) {
    *(float4*)lds = make_float4(v[0], v[1], v[2], v[3]);
}

// TV-L1 thresholding step, branch-free:
//   v = med3(-rho/grad, -l_t, l_t) * g   — agrees exactly with the 3-mask
// reference logic. grad >= EPSF so rcp is safe.
__device__ __forceinline__ void thresh(
    float gx, float gy, float rho, float grad, float l_t,
    float& v1, float& v2)
{
    float s = -rho * __builtin_amdgcn_rcpf(grad);
    float c = __builtin_amdgcn_fmed3f(s, -l_t, l_t);
    v1 = c * gx; v2 = c * gy;
}

// p-pair update at one pixel for one flow (approx sqrt/rcp: err ~2^-22,
// far below the fp16 quantization the state pays at launch boundaries).
__device__ __forceinline__ void pupd(
    float pao, float pbo, float ux, float uy, float taut,
    float& pa, float& pb)
{
    float n2 = fmaf(ux, ux, fmaf(uy, uy, EPSF));
    float n  = __builtin_amdgcn_sqrtf(n2);
    float r  = __builtin_amdgcn_rcpf(fmaf(taut, n, 1.f));
    pa = fmaf(taut, ux, pao) * r;
    pb = fmaf(taut, uy, pbo) * r;
}

// ---------------------------------------------------------------------------
// S: packed g=(gx,gy) fp16x2 and rc fp32 from x,y. Each wave covers one full
// image row: column neighbors come via shuffles.
// ---------------------------------------------------------------------------
__global__ __launch_bounds__(NTHR) void s_kernel(
    const float* __restrict__ x, const float* __restrict__ y,
    __half2* __restrict__ ga, float* __restrict__ rc)
{
    int f = blockIdx.x * NTHR + threadIdx.x;
    int idx = f << 2;
    int i  = (idx >> 8) & 255;

    float4 xc4 = ld4(x, f), yc4 = ld4(y, f);
    const float* xc = (const float*)&xc4;
    const float* yc = (const float*)&yc4;

    float4 a4, b4;                       // wave-uniform row branch
    if (i == 0)            { a4 = ld4(x, f + ROW4); b4 = xc4; }
    else if (i == HH - 1)  { a4 = xc4; b4 = ld4(x, f - ROW4); }
    else                   { a4 = ld4(y, f + ROW4); b4 = ld4(y, f - ROW4); }
    const float* aa = (const float*)&a4;
    const float* bb = (const float*)&b4;

    // column neighbors from adjacent lanes (wave spans the full row)
    float yl = __shfl_up(yc4.w, 1);      // y[idx-1]; lane 0 value unused
    float yr = __shfl_down(yc4.x, 1);    // y[idx+4]; lane 63 value unused

    int j0 = idx & 255;
    float gxo[4], gyo[4], rco[4];
    #pragma unroll
    for (int k = 0; k < 4; ++k) {
        int j = j0 + k;
        float gx;
        if (j == 0)            gx = 0.5f * (xc[1] - xc[0]);
        else if (j == WW - 1)  gx = 0.5f * (xc[3] - xc[2]);
        else {
            float ynext = (k < 3) ? yc[k + 1] : yr;
            float yprev = (k > 0) ? yc[k - 1] : yl;
            gx = 0.5f * (ynext - yprev);
        }
        float gy = 0.5f * (aa[k] - bb[k]);
        gxo[k] = gx; gyo[k] = gy;        // st8h rounds to fp16 (rn) on store
        rco[k] = yc[k] - xc[k];
    }
    st8h(ga, f, gxo, gyo); st4(rc, f, rco);
}

// ---------------------------------------------------------------------------
// FP: 3 fused solver iterations, FIXED row ownership + register-resident
// state. Wave tr owns rel rows {tr-3, tr+5}; u, all four p fields, AND
// ga/rc stay in fp32 registers for the whole kernel -> the main loop has
// ZERO global loads and ZERO fp16 conversions. Cross-wave flows via fp32
// LDS planes: sU1/sU2 (down-row u for p-step), sP12/sP22 (up-row p for
// u-step). Left/right pixel neighbors travel by lane shuffle of registers.
// P0: p(k-1)=0 and u(k)=thresh(ga,rc) in-register. LAST: fp32 u out.
// ---------------------------------------------------------------------------
template <bool P0, bool LAST>
__global__ __launch_bounds__(FTHR, 4) void fp_kernel(
    const __half2* __restrict__ ga, const float* __restrict__ rc,
    const __half2* __restrict__ upi,
    const __half2* __restrict__ pai, const __half2* __restrict__ pbi,
    __half2* __restrict__ upo,
    float* __restrict__ u1f, float* __restrict__ u2f,
    __half2* __restrict__ pao, __half2* __restrict__ pbo,
    const float* __restrict__ tp, const float* __restrict__ lp,
    const float* __restrict__ ap)
{
    __shared__ alignas(16) float sU1[NU ][WW];   // u1, rel rows [-3,10]
    __shared__ alignas(16) float sU2[NU ][WW];   // u2
    __shared__ alignas(16) float sP12[NPR][WW];  // p12, rel rows [-3,9]
    __shared__ alignas(16) float sP22[NPR][WW];  // p22

    const float ts   = tp[0];
    const float l_t  = lp[0] * ts;
    const float taut = ap[0] / ts;

    const int t     = threadIdx.x;
    const int tile  = blockIdx.x;
    const int i0    = (tile & (TPI - 1)) * FTRH;   // tile top row
    const int base4 = (tile / TPI) * (HH * ROW4);  // batch offset, float4 units

    const int tr  = t >> 6;       // wave index 0..7
    const int tcg = t & 63;       // lane
    const int tc  = tcg * 4;

    // persistent per-thread state for the 2 owned rows
    float u1[2][4], u2[2][4];
    float p11[2][4], p12[2][4], p21[2][4], p22[2][4];
    float gxr[2][4], gyr[2][4], rcr[2][4];

    // ---- prologue: load ga/rc/u(k)/p(k-1) into regs; seed sU ----
    #pragma unroll
    for (int s = 0; s < 2; ++s) {
        const int rr = tr - NIT + 8 * s;   // owned rel row: -3..4 / 5..12
        const int gr = i0 + rr;
        const int li = rr + NIT;
        #pragma unroll
        for (int k = 0; k < 4; ++k) {
            u1[s][k]=u2[s][k]=0.f;
            p11[s][k]=p12[s][k]=p21[s][k]=p22[s][k]=0.f;
            gxr[s][k]=gyr[s][k]=rcr[s][k]=0.f;
        }
        // rows > 10 are never consumed: skip their loads entirely
        if (gr >= 0 && gr < HH && rr <= FTRH + 2) {
            const int f = base4 + gr * ROW4 + tcg;
            ld8h(ga, f, gxr[s], gyr[s]);           // cached for all u-steps
            float4 rc4 = ld4(rc, f);
            rcr[s][0]=rc4.x; rcr[s][1]=rc4.y; rcr[s][2]=rc4.z; rcr[s][3]=rc4.w;
            if (P0) {
                #pragma unroll
                for (int k = 0; k < 4; ++k) {
                    float grad = fmaf(gxr[s][k], gxr[s][k],
                                      fmaf(gyr[s][k], gyr[s][k], EPSF));
                    thresh(gxr[s][k], gyr[s][k], rcr[s][k] + EPSF, grad, l_t,
                           u1[s][k], u2[s][k]);    // u(1), div(p0)=0
                }
            } else {
                ld8h(upi, f, u1[s], u2[s]);
            }
            if (!P0 && rr <= FTRH + 1) {   // rows <= 9 can be p-active
                ld8h(pai, f, p11[s], p12[s]);
                ld8h(pbi, f, p21[s], p22[s]);
            }
        }
        if (li < NU) { stp4(&sU1[li][tc], u1[s]); stp4(&sU2[li][tc], u2[s]); }
    }
    __syncthreads();

    #pragma unroll
    for (int m = 0; m < NIT; ++m) {
        const int plo = -(NIT - m);
        const int phi = FTRH - 1 + (NIT - 1 - m);

        // ===== p-step m: rows [plo, phi], in-place on register p =====
        #pragma unroll
        for (int s = 0; s < 2; ++s) {
            const int rr = tr - NIT + 8 * s;
            if (rr < plo || rr > phi) continue;        // wave-uniform
            const int gr = i0 + rr;
            const int li = rr + NIT;
            if (gr >= 0 && gr < HH) {
                const bool hasDn = (gr < HH - 1);
                float u1d[4] = {0,0,0,0}, u2d[4] = {0,0,0,0};
                if (hasDn) { ldp4(&sU1[li + 1][tc], u1d); ldp4(&sU2[li + 1][tc], u2d); }
                const float u1r = __shfl_down(u1[s][0], 1);   // lane+1 px
                const float u2r = __shfl_down(u2[s][0], 1);
                #pragma unroll
                for (int k = 0; k < 4; ++k) {
                    const int j = tc + k;
                    float du1 = (k < 3) ? u1[s][k + 1] : u1r;
                    float du2 = (k < 3) ? u2[s][k + 1] : u2r;
                    float u1x = (j < WW - 1) ? du1 - u1[s][k] : 0.f;
                    float u2x = (j < WW - 1) ? du2 - u2[s][k] : 0.f;
                    float u1y = hasDn ? u1d[k] - u1[s][k] : 0.f;
                    float u2y = hasDn ? u2d[k] - u2[s][k] : 0.f;
                    pupd(p11[s][k], p12[s][k], u1x, u1y, taut,
                         p11[s][k], p12[s][k]);
                    pupd(p21[s][k], p22[s][k], u2x, u2y, taut,
                         p21[s][k], p22[s][k]);
                }
                stp4(&sP12[li][tc], p12[s]);
                stp4(&sP22[li][tc], p22[s]);
                if (m == NIT - 1 && !LAST && rr >= 0 && rr < FTRH) {
                    const int f = base4 + gr * ROW4 + tcg;
                    st8h(pao, f, p11[s], p12[s]);
                    st8h(pbo, f, p21[s], p22[s]);
                }
            } else {
                float z[4] = {0.f, 0.f, 0.f, 0.f};
                stp4(&sP12[li][tc], z);
                stp4(&sP22[li][tc], z);
            }
        }
        __syncthreads();

        // ===== u-step m: rows [plo+1, phi], in-place on register u =====
        const int ulo = plo + 1, uhi = phi;
        #pragma unroll
        for (int s = 0; s < 2; ++s) {
            const int rr = tr - NIT + 8 * s;
            if (rr < ulo || rr > uhi) continue;        // wave-uniform
            const int gr = i0 + rr;
            if (gr < 0 || gr >= HH) continue;          // wave-uniform
            const int li = rr + NIT;
            float q12[4], q22[4];
            ldp4(&sP12[li - 1][tc], q12);              // up-row p, this m
            ldp4(&sP22[li - 1][tc], q22);
            float l11 = __shfl_up(p11[s][3], 1);       // lane-1 px, own row
            float l21 = __shfl_up(p21[s][3], 1);
            if (tcg == 0) { l11 = 0.f; l21 = 0.f; }    // j==0 boundary
            const bool hasDn = (gr < HH - 1);
            #pragma unroll
            for (int k = 0; k < 4; ++k) {
                const int j = tc + k;
                float t11  = (j < WW - 1) ? p11[s][k] : 0.f;
                float t21  = (j < WW - 1) ? p21[s][k] : 0.f;
                float l11k = (k == 0) ? l11 : p11[s][k - 1];
                float l21k = (k == 0) ? l21 : p21[s][k - 1];
                float t12  = hasDn ? p12[s][k] : 0.f;
                float t22  = hasDn ? p22[s][k] : 0.f;
                float div1 = (t11 - l11k) + (t12 - q12[k]);
                float div2 = (t21 - l21k) + (t22 - q22[k]);

                float grad = fmaf(gxr[s][k], gxr[s][k],
                                  fmaf(gyr[s][k], gyr[s][k], EPSF));
                float rho  = rcr[s][k] + gxr[s][k]*u1[s][k]
                                       + gyr[s][k]*u2[s][k] + EPSF;
                float v1, v2;
                thresh(gxr[s][k], gyr[s][k], rho, grad, l_t, v1, v2);
                u1[s][k] = v1 + u1[s][k] + ts * div1;
                u2[s][k] = v2 + u2[s][k] + ts * div2;
            }
            if (m == NIT - 1) {
                const int f = base4 + gr * ROW4 + tcg;
                if (LAST) { st4(u1f, f, u1[s]); st4(u2f, f, u2[s]); }
                else      { st8h(upo, f, u1[s], u2[s]); }
            } else {
                stp4(&sU1[li][tc], u1[s]);
                stp4(&sU2[li][tc], u2[s]);
            }
        }
        if (m < NIT - 1) __syncthreads();
    }
}

// ---------------------------------------------------------------------------
extern "C" void kernel_launch(void* const* d_in, const int* in_sizes, int n_in,
                              void* d_out, int out_size, void* d_ws, size_t ws_size,
                              hipStream_t stream) {
    const float* x = (const float*)d_in[0];
    const float* y = (const float*)d_in[1];
    const float* t = (const float*)d_in[8];
    const float* l = (const float*)d_in[9];
    const float* a = (const float*)d_in[10];

    float* u1out = (float*)d_out;
    float* u2out = u1out + NPIX;

    // ws: rc(f32) + 7 packed half2 fields = 8 * 16.8 MB = 134 MB
    char* ws = (char*)d_ws;
    float*   rcp_ = (float*)ws;                              ws += (size_t)NPIX * 4;
    __half2* gaP  = (__half2*)ws;                            ws += (size_t)NPIX * 4;
    __half2* upA  = (__half2*)ws;                            ws += (size_t)NPIX * 4;
    __half2* upB  = (__half2*)ws;                            ws += (size_t)NPIX * 4;
    __half2* paA  = (__half2*)ws;                            ws += (size_t)NPIX * 4;
    __half2* pbA  = (__half2*)ws;                            ws += (size_t)NPIX * 4;
    __half2* paB  = (__half2*)ws;                            ws += (size_t)NPIX * 4;
    __half2* pbB  = (__half2*)ws;

    // S: ga, rc only (u(1) recomputed in FP1)
    s_kernel<<<dim3(NBLK), dim3(NTHR), 0, stream>>>(x, y, gaP, rcp_);

    // FP1: iterations 1-3  (p1..p3, u2..u4), p0 = 0, u1 in-register
    fp_kernel<true, false><<<dim3(FBLK), dim3(FTHR), 0, stream>>>(
        gaP, rcp_, nullptr, nullptr, nullptr,
        upA, nullptr, nullptr, paA, pbA, t, l, a);

    // FP2: iterations 4-6  (p4..p6, u5..u7)
    fp_kernel<false, false><<<dim3(FBLK), dim3(FTHR), 0, stream>>>(
        gaP, rcp_, upA, paA, pbA,
        upB, nullptr, nullptr, paB, pbB, t, l, a);

    // FP3: iterations 7-9 + final u(10) as fp32; dead p(9) store skipped
    fp_kernel<false, true><<<dim3(FBLK), dim3(FTHR), 0, stream>>>(
        gaP, rcp_, upB, paB, pbB,
        nullptr, u1out, u2out, nullptr, nullptr, t, l, a);
}

// Round 9
// 226.243 us; speedup vs baseline: 1.2170x; 1.0255x over previous
//
#include <hip/hip_runtime.h>
#include <hip/hip_fp16.h>

#define HH 256
#define WW 256
#define NB 64
#define NPIX (NB * HH * WW)      // 4,194,304 pixels
#define NF4  (NPIX / 4)          // 1,048,576 groups of 4
#define ROW4 (WW / 4)            // 64 groups per image row
#define EPSF 1e-12f
#define NTHR 256
#define NBLK (NF4 / NTHR)        // 4096 blocks (S kernel, flat)
#define FTRH 8                   // output rows per tile
#define FTHR 512                 // 8 waves
#define TPI  (HH / FTRH)         // 32 tiles per image
#define FBLK (NB * TPI)          // 2048 blocks (FP kernel)
#define NIT  3                   // solver iterations fused per FP launch
#define NU   (FTRH + 2 * NIT)        // 14 LDS u rows, rel [-3,10]
#define NPR  (FTRH + 2 * NIT - 1)    // 13 LDS p12/p22 rows, rel [-3,9]
// LDS: fp32 planes sU1,sU2 (14 rows) + sP12,sP22 (13 rows) = 55.3 KB.
// __launch_bounds__(512,4): 128-reg budget (unified VGPR+AGPR on gfx950).
// NOTE: round-7/8's readfirstlane guard-scalarization is REMOVED — two
// consecutive container failures with it; this is round-6's proven
// structure + iteration-invariant rg=rcp(grad) + EPSF folded into rc.

__device__ __forceinline__ float4 ld4(const float* p, int f) {
    return ((const float4*)p)[f];
}
__device__ __forceinline__ void st4(float* p, int f, const float* v) {
    ((float4*)p)[f] = make_float4(v[0], v[1], v[2], v[3]);
}
// Packed-pair load: 4 pixels of a __half2 field (16B) -> two float[4]
__device__ __forceinline__ void ld8h(const __half2* p, int f, float* a, float* b) {
    float4 raw = ((const float4*)p)[f];
    const __half2* h = (const __half2*)&raw;
    #pragma unroll
    for (int k = 0; k < 4; ++k) {
        float2 v = __half22float2(h[k]);
        a[k] = v.x; b[k] = v.y;
    }
}
__device__ __forceinline__ void st8h(__half2* p, int f, const float* a, const float* b) {
    float4 raw;
    __half2* h = (__half2*)&raw;
    #pragma unroll
    for (int k = 0; k < 4; ++k) h[k] = __floats2half2_rn(a[k], b[k]);
    ((float4*)p)[f] = raw;
}
// float[4] <-> float4 helpers for fp32 LDS planes
__device__ __forceinline__ void ldp4(const float* lds, float* v) {
    float4 r = *(const float4*)lds;
    v[0] = r.x; v[1] = r.y; v[2] = r.z; v[3] = r.w;
}
__device__ __forceinline__ void stp4(float* lds, const float* v) {
    *(float4*)lds = make_float4(v[0], v[1], v[2], v[3]);
}

// TV-L1 thresholding with precomputed rg = 1/grad:
//   v = med3(-rho*rg, -l_t, l_t) * g   — agrees exactly with the 3-mask
// reference logic (see round-1 note).
__device__ __forceinline__ void thresh_rg(
    float gx, float gy, float rho, float rg, float l_t,
    float& v1, float& v2)
{
    float s = -rho * rg;
    float c = __builtin_amdgcn_fmed3f(s, -l_t, l_t);
    v1 = c * gx; v2 = c * gy;
}

// p-pair update at one pixel for one flow (approx sqrt/rcp: err ~2^-22,
// far below the fp16 quantization the state pays at launch boundaries).
__device__ __forceinline__ void pupd(
    float pao, float pbo, float ux, float uy, float taut,
    float& pa, float& pb)
{
    float n2 = fmaf(ux, ux, fmaf(uy, uy, EPSF));
    float n  = __builtin_amdgcn_sqrtf(n2);
    float r  = __builtin_amdgcn_rcpf(fmaf(taut, n, 1.f));
    pa = fmaf(taut, ux, pao) * r;
    pb = fmaf(taut, uy, pbo) * r;
}

// ---------------------------------------------------------------------------
// S: packed g=(gx,gy) fp16x2 and rc fp32 from x,y. Each wave covers one full
// image row: column neighbors come via shuffles.
// ---------------------------------------------------------------------------
__global__ __launch_bounds__(NTHR) void s_kernel(
    const float* __restrict__ x, const float* __restrict__ y,
    __half2* __restrict__ ga, float* __restrict__ rc)
{
    int f = blockIdx.x * NTHR + threadIdx.x;
    int idx = f << 2;
    int i  = (idx >> 8) & 255;

    float4 xc4 = ld4(x, f), yc4 = ld4(y, f);
    const float* xc = (const float*)&xc4;
    const float* yc = (const float*)&yc4;

    float4 a4, b4;                       // wave-uniform row branch
    if (i == 0)            { a4 = ld4(x, f + ROW4); b4 = xc4; }
    else if (i == HH - 1)  { a4 = xc4; b4 = ld4(x, f - ROW4); }
    else                   { a4 = ld4(y, f + ROW4); b4 = ld4(y, f - ROW4); }
    const float* aa = (const float*)&a4;
    const float* bb = (const float*)&b4;

    // column neighbors from adjacent lanes (wave spans the full row)
    float yl = __shfl_up(yc4.w, 1);      // y[idx-1]; lane 0 value unused
    float yr = __shfl_down(yc4.x, 1);    // y[idx+4]; lane 63 value unused

    int j0 = idx & 255;
    float gxo[4], gyo[4], rco[4];
    #pragma unroll
    for (int k = 0; k < 4; ++k) {
        int j = j0 + k;
        float gx;
        if (j == 0)            gx = 0.5f * (xc[1] - xc[0]);
        else if (j == WW - 1)  gx = 0.5f * (xc[3] - xc[2]);
        else {
            float ynext = (k < 3) ? yc[k + 1] : yr;
            float yprev = (k > 0) ? yc[k - 1] : yl;
            gx = 0.5f * (ynext - yprev);
        }
        float gy = 0.5f * (aa[k] - bb[k]);
        gxo[k] = gx; gyo[k] = gy;        // st8h rounds to fp16 (rn) on store
        rco[k] = yc[k] - xc[k];
    }
    st8h(ga, f, gxo, gyo); st4(rc, f, rco);
}

// ---------------------------------------------------------------------------
// FP: 3 fused solver iterations, FIXED row ownership + register-resident
// state. Wave tr owns rel rows {tr-3, tr+5}; u, p, ga, rc(+EPSF), rg stay
// in registers; main loop has zero global loads / zero fp16 conversions.
// Cross-wave flows via fp32 LDS planes sU1/sU2 and sP12/sP22.
// P0: p(k-1)=0 and u(k)=thresh(ga,rc) in-register. LAST: fp32 u out.
// ---------------------------------------------------------------------------
template <bool P0, bool LAST>
__global__ __launch_bounds__(FTHR, 4) void fp_kernel(
    const __half2* __restrict__ ga, const float* __restrict__ rc,
    const __half2* __restrict__ upi,
    const __half2* __restrict__ pai, const __half2* __restrict__ pbi,
    __half2* __restrict__ upo,
    float* __restrict__ u1f, float* __restrict__ u2f,
    __half2* __restrict__ pao, __half2* __restrict__ pbo,
    const float* __restrict__ tp, const float* __restrict__ lp,
    const float* __restrict__ ap)
{
    __shared__ alignas(16) float sU1[NU ][WW];   // u1, rel rows [-3,10]
    __shared__ alignas(16) float sU2[NU ][WW];   // u2
    __shared__ alignas(16) float sP12[NPR][WW];  // p12, rel rows [-3,9]
    __shared__ alignas(16) float sP22[NPR][WW];  // p22

    const float ts   = tp[0];
    const float l_t  = lp[0] * ts;
    const float taut = ap[0] / ts;

    const int t     = threadIdx.x;
    const int tile  = blockIdx.x;
    const int i0    = (tile & (TPI - 1)) * FTRH;   // tile top row
    const int base4 = (tile / TPI) * (HH * ROW4);  // batch offset, float4 units

    const int tr  = t >> 6;       // wave index 0..7
    const int tcg = t & 63;       // lane
    const int tc  = tcg * 4;

    // persistent per-thread state for the 2 owned rows
    float u1[2][4], u2[2][4];
    float p11[2][4], p12[2][4], p21[2][4], p22[2][4];
    float gxr[2][4], gyr[2][4], rcr[2][4], rgr[2][4];

    // ---- prologue: load ga/rc/u(k)/p(k-1) into regs; seed sU ----
    #pragma unroll
    for (int s = 0; s < 2; ++s) {
        const int rr = tr - NIT + 8 * s;   // owned rel row: -3..4 / 5..12
        const int gr = i0 + rr;
        const int li = rr + NIT;
        #pragma unroll
        for (int k = 0; k < 4; ++k) {
            u1[s][k]=u2[s][k]=0.f;
            p11[s][k]=p12[s][k]=p21[s][k]=p22[s][k]=0.f;
            gxr[s][k]=gyr[s][k]=rcr[s][k]=0.f; rgr[s][k]=1.f;
        }
        // rows > 10 are never consumed: skip their loads entirely
        if (gr >= 0 && gr < HH && rr <= FTRH + 2) {
            const int f = base4 + gr * ROW4 + tcg;
            ld8h(ga, f, gxr[s], gyr[s]);           // cached for all u-steps
            float4 rc4 = ld4(rc, f);
            rcr[s][0]=rc4.x+EPSF; rcr[s][1]=rc4.y+EPSF;
            rcr[s][2]=rc4.z+EPSF; rcr[s][3]=rc4.w+EPSF;
            #pragma unroll
            for (int k = 0; k < 4; ++k) {
                float grad = fmaf(gxr[s][k], gxr[s][k],
                                  fmaf(gyr[s][k], gyr[s][k], EPSF));
                rgr[s][k] = __builtin_amdgcn_rcpf(grad);   // iter-invariant
            }
            if (P0) {
                #pragma unroll
                for (int k = 0; k < 4; ++k) {
                    thresh_rg(gxr[s][k], gyr[s][k], rcr[s][k], rgr[s][k], l_t,
                              u1[s][k], u2[s][k]);  // u(1), div(p0)=0
                }
            } else {
                ld8h(upi, f, u1[s], u2[s]);
            }
            if (!P0 && rr <= FTRH + 1) {   // rows <= 9 can be p-active
                ld8h(pai, f, p11[s], p12[s]);
                ld8h(pbi, f, p21[s], p22[s]);
            }
        }
        if (li < NU) { stp4(&sU1[li][tc], u1[s]); stp4(&sU2[li][tc], u2[s]); }
    }
    __syncthreads();

    #pragma unroll
    for (int m = 0; m < NIT; ++m) {
        const int plo = -(NIT - m);
        const int phi = FTRH - 1 + (NIT - 1 - m);

        // ===== p-step m: rows [plo, phi], in-place on register p =====
        #pragma unroll
        for (int s = 0; s < 2; ++s) {
            const int rr = tr - NIT + 8 * s;
            if (rr < plo || rr > phi) continue;        // wave-uniform
            const int gr = i0 + rr;
            const int li = rr + NIT;
            if (gr >= 0 && gr < HH) {
                const bool hasDn = (gr < HH - 1);
                float u1d[4] = {0,0,0,0}, u2d[4] = {0,0,0,0};
                if (hasDn) { ldp4(&sU1[li + 1][tc], u1d); ldp4(&sU2[li + 1][tc], u2d); }
                const float u1r = __shfl_down(u1[s][0], 1);   // lane+1 px
                const float u2r = __shfl_down(u2[s][0], 1);
                #pragma unroll
                for (int k = 0; k < 4; ++k) {
                    const int j = tc + k;
                    float du1 = (k < 3) ? u1[s][k + 1] : u1r;
                    float du2 = (k < 3) ? u2[s][k + 1] : u2r;
                    float u1x = (j < WW - 1) ? du1 - u1[s][k] : 0.f;
                    float u2x = (j < WW - 1) ? du2 - u2[s][k] : 0.f;
                    float u1y = hasDn ? u1d[k] - u1[s][k] : 0.f;
                    float u2y = hasDn ? u2d[k] - u2[s][k] : 0.f;
                    pupd(p11[s][k], p12[s][k], u1x, u1y, taut,
                         p11[s][k], p12[s][k]);
                    pupd(p21[s][k], p22[s][k], u2x, u2y, taut,
                         p21[s][k], p22[s][k]);
                }
                stp4(&sP12[li][tc], p12[s]);
                stp4(&sP22[li][tc], p22[s]);
                if (m == NIT - 1 && !LAST && rr >= 0 && rr < FTRH) {
                    const int f = base4 + gr * ROW4 + tcg;
                    st8h(pao, f, p11[s], p12[s]);
                    st8h(pbo, f, p21[s], p22[s]);
                }
            } else {
                float z[4] = {0.f, 0.f, 0.f, 0.f};
                stp4(&sP12[li][tc], z);
                stp4(&sP22[li][tc], z);
            }
        }
        __syncthreads();

        // ===== u-step m: rows [plo+1, phi], in-place on register u =====
        const int ulo = plo + 1, uhi = phi;
        #pragma unroll
        for (int s = 0; s < 2; ++s) {
            const int rr = tr - NIT + 8 * s;
            if (rr < ulo || rr > uhi) continue;        // wave-uniform
            const int gr = i0 + rr;
            if (gr < 0 || gr >= HH) continue;          // wave-uniform
            const int li = rr + NIT;
            float q12[4], q22[4];
            ldp4(&sP12[li - 1][tc], q12);              // up-row p, this m
            ldp4(&sP22[li - 1][tc], q22);
            float l11 = __shfl_up(p11[s][3], 1);       // lane-1 px, own row
            float l21 = __shfl_up(p21[s][3], 1);
            if (tcg == 0) { l11 = 0.f; l21 = 0.f; }    // j==0 boundary
            const bool hasDn = (gr < HH - 1);
            #pragma unroll
            for (int k = 0; k < 4; ++k) {
                const int j = tc + k;
                float t11  = (j < WW - 1) ? p11[s][k] : 0.f;
                float t21  = (j < WW - 1) ? p21[s][k] : 0.f;
                float l11k = (k == 0) ? l11 : p11[s][k - 1];
                float l21k = (k == 0) ? l21 : p21[s][k - 1];
                float t12  = hasDn ? p12[s][k] : 0.f;
                float t22  = hasDn ? p22[s][k] : 0.f;
                float div1 = (t11 - l11k) + (t12 - q12[k]);
                float div2 = (t21 - l21k) + (t22 - q22[k]);

                float rho  = rcr[s][k] + gxr[s][k]*u1[s][k]
                                       + gyr[s][k]*u2[s][k];
                float v1, v2;
                thresh_rg(gxr[s][k], gyr[s][k], rho, rgr[s][k], l_t, v1, v2);
                u1[s][k] = v1 + u1[s][k] + ts * div1;
                u2[s][k] = v2 + u2[s][k] + ts * div2;
            }
            if (m == NIT - 1) {
                const int f = base4 + gr * ROW4 + tcg;
                if (LAST) { st4(u1f, f, u1[s]); st4(u2f, f, u2[s]); }
                else      { st8h(upo, f, u1[s], u2[s]); }
            } else {
                stp4(&sU1[li][tc], u1[s]);
                stp4(&sU2[li][tc], u2[s]);
            }
        }
        if (m < NIT - 1) __syncthreads();
    }
}

// ---------------------------------------------------------------------------
extern "C" void kernel_launch(void* const* d_in, const int* in_sizes, int n_in,
                              void* d_out, int out_size, void* d_ws, size_t ws_size,
                              hipStream_t stream) {
    const float* x = (const float*)d_in[0];
    const float* y = (const float*)d_in[1];
    const float* t = (const float*)d_in[8];
    const float* l = (const float*)d_in[9];
    const float* a = (const float*)d_in[10];

    float* u1out = (float*)d_out;
    float* u2out = u1out + NPIX;

    // ws: rc(f32) + 7 packed half2 fields = 8 * 16.8 MB = 134 MB
    char* ws = (char*)d_ws;
    float*   rcp_ = (float*)ws;                              ws += (size_t)NPIX * 4;
    __half2* gaP  = (__half2*)ws;                            ws += (size_t)NPIX * 4;
    __half2* upA  = (__half2*)ws;                            ws += (size_t)NPIX * 4;
    __half2* upB  = (__half2*)ws;                            ws += (size_t)NPIX * 4;
    __half2* paA  = (__half2*)ws;                            ws += (size_t)NPIX * 4;
    __half2* pbA  = (__half2*)ws;                            ws += (size_t)NPIX * 4;
    __half2* paB  = (__half2*)ws;                            ws += (size_t)NPIX * 4;
    __half2* pbB  = (__half2*)ws;

    // S: ga, rc only (u(1) recomputed in FP1)
    s_kernel<<<dim3(NBLK), dim3(NTHR), 0, stream>>>(x, y, gaP, rcp_);

    // FP1: iterations 1-3  (p1..p3, u2..u4), p0 = 0, u1 in-register
    fp_kernel<true, false><<<dim3(FBLK), dim3(FTHR), 0, stream>>>(
        gaP, rcp_, nullptr, nullptr, nullptr,
        upA, nullptr, nullptr, paA, pbA, t, l, a);

    // FP2: iterations 4-6  (p4..p6, u5..u7)
    fp_kernel<false, false><<<dim3(FBLK), dim3(FTHR), 0, stream>>>(
        gaP, rcp_, upA, paA, pbA,
        upB, nullptr, nullptr, paB, pbB, t, l, a);

    // FP3: iterations 7-9 + final u(10) as fp32; dead p(9) store skipped
    fp_kernel<false, true><<<dim3(FBLK), dim3(FTHR), 0, stream>>>(
        gaP, rcp_, upB, paB, pbB,
        nullptr, u1out, u2out, nullptr, nullptr, t, l, a);
}

// Round 10
// 220.763 us; speedup vs baseline: 1.2472x; 1.0248x over previous
//
#include <hip/hip_runtime.h>
#include <hip/hip_fp16.h>

#define HH 256
#define WW 256
#define NB 64
#define NPIX (NB * HH * WW)      // 4,194,304 pixels
#define NF4  (NPIX / 4)          // 1,048,576 groups of 4
#define ROW4 (WW / 4)            // 64 groups per image row
#define EPSF 1e-12f
#define FTRH 8                   // output rows per tile
#define FTHR 512                 // 8 waves
#define TPI  (HH / FTRH)         // 32 tiles per image
#define FBLK (NB * TPI)          // 2048 blocks (FP kernel)
#define NIT  3                   // solver iterations fused per FP launch
#define NU   (FTRH + 2 * NIT)        // 14 LDS u rows, rel [-3,10]
#define NPR  (FTRH + 2 * NIT - 1)    // 13 LDS p12/p22 rows, rel [-3,9]
// LDS: fp32 planes sU1,sU2 (14 rows) + sP12,sP22 (13 rows) = 55.3 KB.
// __launch_bounds__(512,4): 128-reg budget (unified VGPR+AGPR on gfx950).
// This round: the S kernel is FUSED into FP1's prologue — each wave spans
// a full row, so ga=(gx,gy) and rc=y-x are computed from x,y in-register
// (same shuffle/boundary logic s_kernel used), quantized to fp16 to match
// FP2/FP3's readback path, and written to global (own rows only,
// exactly-once coverage). One fewer dispatch + no ga/rc round-trip for
// iterations 1-3. FP2/FP3 are byte-identical to round 9 (passed, 226 µs).

__device__ __forceinline__ float4 ld4(const float* p, int f) {
    return ((const float4*)p)[f];
}
__device__ __forceinline__ void st4(float* p, int f, const float* v) {
    ((float4*)p)[f] = make_float4(v[0], v[1], v[2], v[3]);
}
// Packed-pair load: 4 pixels of a __half2 field (16B) -> two float[4]
__device__ __forceinline__ void ld8h(const __half2* p, int f, float* a, float* b) {
    float4 raw = ((const float4*)p)[f];
    const __half2* h = (const __half2*)&raw;
    #pragma unroll
    for (int k = 0; k < 4; ++k) {
        float2 v = __half22float2(h[k]);
        a[k] = v.x; b[k] = v.y;
    }
}
__device__ __forceinline__ void st8h(__half2* p, int f, const float* a, const float* b) {
    float4 raw;
    __half2* h = (__half2*)&raw;
    #pragma unroll
    for (int k = 0; k < 4; ++k) h[k] = __floats2half2_rn(a[k], b[k]);
    ((float4*)p)[f] = raw;
}
// float[4] <-> float4 helpers for fp32 LDS planes
__device__ __forceinline__ void ldp4(const float* lds, float* v) {
    float4 r = *(const float4*)lds;
    v[0] = r.x; v[1] = r.y; v[2] = r.z; v[3] = r.w;
}
__device__ __forceinline__ void stp4(float* lds, const float* v) {
    *(float4*)lds = make_float4(v[0], v[1], v[2], v[3]);
}

// TV-L1 thresholding with precomputed rg = 1/grad:
//   v = med3(-rho*rg, -l_t, l_t) * g   — agrees exactly with the 3-mask
// reference logic (see round-1 note).
__device__ __forceinline__ void thresh_rg(
    float gx, float gy, float rho, float rg, float l_t,
    float& v1, float& v2)
{
    float s = -rho * rg;
    float c = __builtin_amdgcn_fmed3f(s, -l_t, l_t);
    v1 = c * gx; v2 = c * gy;
}

// p-pair update at one pixel for one flow (approx sqrt/rcp: err ~2^-22,
// far below the fp16 quantization the state pays at launch boundaries).
__device__ __forceinline__ void pupd(
    float pao, float pbo, float ux, float uy, float taut,
    float& pa, float& pb)
{
    float n2 = fmaf(ux, ux, fmaf(uy, uy, EPSF));
    float n  = __builtin_amdgcn_sqrtf(n2);
    float r  = __builtin_amdgcn_rcpf(fmaf(taut, n, 1.f));
    pa = fmaf(taut, ux, pao) * r;
    pb = fmaf(taut, uy, pbo) * r;
}

// ---------------------------------------------------------------------------
// FP: 3 fused solver iterations, FIXED row ownership + register-resident
// state. Wave tr owns rel rows {tr-3, tr+5}; u, p, ga, rc(+EPSF), rg stay
// in registers; main loop has zero global loads / zero fp16 conversions.
// Cross-wave flows via fp32 LDS planes sU1/sU2 and sP12/sP22.
// P0: ga/rc computed in-prologue from x,y (s_kernel fused), written to
// global for FP2/FP3; p(k-1)=0, u(k)=thresh in-register.
// LAST: fp32 u out, dead p store skipped.
// ---------------------------------------------------------------------------
template <bool P0, bool LAST>
__global__ __launch_bounds__(FTHR, 4) void fp_kernel(
    const __half2* __restrict__ ga, const float* __restrict__ rc,
    const __half2* __restrict__ upi,
    const __half2* __restrict__ pai, const __half2* __restrict__ pbi,
    __half2* __restrict__ upo,
    float* __restrict__ u1f, float* __restrict__ u2f,
    __half2* __restrict__ pao, __half2* __restrict__ pbo,
    const float* __restrict__ tp, const float* __restrict__ lp,
    const float* __restrict__ ap,
    const float* __restrict__ xg, const float* __restrict__ yg,
    __half2* __restrict__ gao, float* __restrict__ rco)
{
    __shared__ alignas(16) float sU1[NU ][WW];   // u1, rel rows [-3,10]
    __shared__ alignas(16) float sU2[NU ][WW];   // u2
    __shared__ alignas(16) float sP12[NPR][WW];  // p12, rel rows [-3,9]
    __shared__ alignas(16) float sP22[NPR][WW];  // p22

    const float ts   = tp[0];
    const float l_t  = lp[0] * ts;
    const float taut = ap[0] / ts;

    const int t     = threadIdx.x;
    const int tile  = blockIdx.x;
    const int i0    = (tile & (TPI - 1)) * FTRH;   // tile top row
    const int base4 = (tile / TPI) * (HH * ROW4);  // batch offset, float4 units

    const int tr  = t >> 6;       // wave index 0..7
    const int tcg = t & 63;       // lane
    const int tc  = tcg * 4;

    // persistent per-thread state for the 2 owned rows
    float u1[2][4], u2[2][4];
    float p11[2][4], p12[2][4], p21[2][4], p22[2][4];
    float gxr[2][4], gyr[2][4], rcr[2][4], rgr[2][4];

    // ---- prologue: ga/rc/u(k)/p(k-1) into regs; seed sU ----
    #pragma unroll
    for (int s = 0; s < 2; ++s) {
        const int rr = tr - NIT + 8 * s;   // owned rel row: -3..4 / 5..12
        const int gr = i0 + rr;
        const int li = rr + NIT;
        #pragma unroll
        for (int k = 0; k < 4; ++k) {
            u1[s][k]=u2[s][k]=0.f;
            p11[s][k]=p12[s][k]=p21[s][k]=p22[s][k]=0.f;
            gxr[s][k]=gyr[s][k]=rcr[s][k]=0.f; rgr[s][k]=1.f;
        }
        // rows > 10 are never consumed: skip their loads entirely
        if (gr >= 0 && gr < HH && rr <= FTRH + 2) {
            const int f = base4 + gr * ROW4 + tcg;
            if (P0) {
                // ---- fused s_kernel: ga/rc from x,y (wave spans the row) ----
                float4 xc4 = ld4(xg, f), yc4 = ld4(yg, f);
                const float* xc = (const float*)&xc4;
                const float* yc = (const float*)&yc4;
                float4 a4, b4;                     // wave-uniform row branch
                if (gr == 0)           { a4 = ld4(xg, f + ROW4); b4 = xc4; }
                else if (gr == HH - 1) { a4 = xc4; b4 = ld4(xg, f - ROW4); }
                else                   { a4 = ld4(yg, f + ROW4); b4 = ld4(yg, f - ROW4); }
                const float* aa = (const float*)&a4;
                const float* bb = (const float*)&b4;
                float yl = __shfl_up(yc4.w, 1);    // lane 0 value unused (j==0)
                float yr = __shfl_down(yc4.x, 1);  // lane 63 value unused
                float rcg[4];
                #pragma unroll
                for (int k = 0; k < 4; ++k) {
                    const int j = tc + k;
                    float gx;
                    if (j == 0)            gx = 0.5f * (xc[1] - xc[0]);
                    else if (j == WW - 1)  gx = 0.5f * (xc[3] - xc[2]);
                    else {
                        float ynext = (k < 3) ? yc[k + 1] : yr;
                        float yprev = (k > 0) ? yc[k - 1] : yl;
                        gx = 0.5f * (ynext - yprev);
                    }
                    float gy = 0.5f * (aa[k] - bb[k]);
                    // quantize NOW so FP1 matches FP2/FP3's fp16 readback
                    gxr[s][k] = __half2float(__float2half_rn(gx));
                    gyr[s][k] = __half2float(__float2half_rn(gy));
                    rcg[k]    = yc[k] - xc[k];
                    rcr[s][k] = rcg[k] + EPSF;
                }
                // write ga/rc for FP2/FP3 (own rows only: exactly-once)
                if (rr >= 0 && rr < FTRH) {
                    st8h(gao, f, gxr[s], gyr[s]);  // values already fp16-exact
                    st4(rco, f, rcg);
                }
            } else {
                ld8h(ga, f, gxr[s], gyr[s]);       // cached for all u-steps
                float4 rc4 = ld4(rc, f);
                rcr[s][0]=rc4.x+EPSF; rcr[s][1]=rc4.y+EPSF;
                rcr[s][2]=rc4.z+EPSF; rcr[s][3]=rc4.w+EPSF;
            }
            #pragma unroll
            for (int k = 0; k < 4; ++k) {
                float grad = fmaf(gxr[s][k], gxr[s][k],
                                  fmaf(gyr[s][k], gyr[s][k], EPSF));
                rgr[s][k] = __builtin_amdgcn_rcpf(grad);   // iter-invariant
            }
            if (P0) {
                #pragma unroll
                for (int k = 0; k < 4; ++k) {
                    thresh_rg(gxr[s][k], gyr[s][k], rcr[s][k], rgr[s][k], l_t,
                              u1[s][k], u2[s][k]);  // u(1), div(p0)=0
                }
            } else {
                ld8h(upi, f, u1[s], u2[s]);
            }
            if (!P0 && rr <= FTRH + 1) {   // rows <= 9 can be p-active
                ld8h(pai, f, p11[s], p12[s]);
                ld8h(pbi, f, p21[s], p22[s]);
            }
        }
        if (li < NU) { stp4(&sU1[li][tc], u1[s]); stp4(&sU2[li][tc], u2[s]); }
    }
    __syncthreads();

    #pragma unroll
    for (int m = 0; m < NIT; ++m) {
        const int plo = -(NIT - m);
        const int phi = FTRH - 1 + (NIT - 1 - m);

        // ===== p-step m: rows [plo, phi], in-place on register p =====
        #pragma unroll
        for (int s = 0; s < 2; ++s) {
            const int rr = tr - NIT + 8 * s;
            if (rr < plo || rr > phi) continue;        // wave-uniform
            const int gr = i0 + rr;
            const int li = rr + NIT;
            if (gr >= 0 && gr < HH) {
                const bool hasDn = (gr < HH - 1);
                float u1d[4] = {0,0,0,0}, u2d[4] = {0,0,0,0};
                if (hasDn) { ldp4(&sU1[li + 1][tc], u1d); ldp4(&sU2[li + 1][tc], u2d); }
                const float u1r = __shfl_down(u1[s][0], 1);   // lane+1 px
                const float u2r = __shfl_down(u2[s][0], 1);
                #pragma unroll
                for (int k = 0; k < 4; ++k) {
                    const int j = tc + k;
                    float du1 = (k < 3) ? u1[s][k + 1] : u1r;
                    float du2 = (k < 3) ? u2[s][k + 1] : u2r;
                    float u1x = (j < WW - 1) ? du1 - u1[s][k] : 0.f;
                    float u2x = (j < WW - 1) ? du2 - u2[s][k] : 0.f;
                    float u1y = hasDn ? u1d[k] - u1[s][k] : 0.f;
                    float u2y = hasDn ? u2d[k] - u2[s][k] : 0.f;
                    pupd(p11[s][k], p12[s][k], u1x, u1y, taut,
                         p11[s][k], p12[s][k]);
                    pupd(p21[s][k], p22[s][k], u2x, u2y, taut,
                         p21[s][k], p22[s][k]);
                }
                stp4(&sP12[li][tc], p12[s]);
                stp4(&sP22[li][tc], p22[s]);
                if (m == NIT - 1 && !LAST && rr >= 0 && rr < FTRH) {
                    const int f = base4 + gr * ROW4 + tcg;
                    st8h(pao, f, p11[s], p12[s]);
                    st8h(pbo, f, p21[s], p22[s]);
                }
            } else {
                float z[4] = {0.f, 0.f, 0.f, 0.f};
                stp4(&sP12[li][tc], z);
                stp4(&sP22[li][tc], z);
            }
        }
        __syncthreads();

        // ===== u-step m: rows [plo+1, phi], in-place on register u =====
        const int ulo = plo + 1, uhi = phi;
        #pragma unroll
        for (int s = 0; s < 2; ++s) {
            const int rr = tr - NIT + 8 * s;
            if (rr < ulo || rr > uhi) continue;        // wave-uniform
            const int gr = i0 + rr;
            if (gr < 0 || gr >= HH) continue;          // wave-uniform
            const int li = rr + NIT;
            float q12[4], q22[4];
            ldp4(&sP12[li - 1][tc], q12);              // up-row p, this m
            ldp4(&sP22[li - 1][tc], q22);
            float l11 = __shfl_up(p11[s][3], 1);       // lane-1 px, own row
            float l21 = __shfl_up(p21[s][3], 1);
            if (tcg == 0) { l11 = 0.f; l21 = 0.f; }    // j==0 boundary
            const bool hasDn = (gr < HH - 1);
            #pragma unroll
            for (int k = 0; k < 4; ++k) {
                const int j = tc + k;
                float t11  = (j < WW - 1) ? p11[s][k] : 0.f;
                float t21  = (j < WW - 1) ? p21[s][k] : 0.f;
                float l11k = (k == 0) ? l11 : p11[s][k - 1];
                float l21k = (k == 0) ? l21 : p21[s][k - 1];
                float t12  = hasDn ? p12[s][k] : 0.f;
                float t22  = hasDn ? p22[s][k] : 0.f;
                float div1 = (t11 - l11k) + (t12 - q12[k]);
                float div2 = (t21 - l21k) + (t22 - q22[k]);

                float rho  = rcr[s][k] + gxr[s][k]*u1[s][k]
                                       + gyr[s][k]*u2[s][k];
                float v1, v2;
                thresh_rg(gxr[s][k], gyr[s][k], rho, rgr[s][k], l_t, v1, v2);
                u1[s][k] = v1 + u1[s][k] + ts * div1;
                u2[s][k] = v2 + u2[s][k] + ts * div2;
            }
            if (m == NIT - 1) {
                const int f = base4 + gr * ROW4 + tcg;
                if (LAST) { st4(u1f, f, u1[s]); st4(u2f, f, u2[s]); }
                else      { st8h(upo, f, u1[s], u2[s]); }
            } else {
                stp4(&sU1[li][tc], u1[s]);
                stp4(&sU2[li][tc], u2[s]);
            }
        }
        if (m < NIT - 1) __syncthreads();
    }
}

// ---------------------------------------------------------------------------
extern "C" void kernel_launch(void* const* d_in, const int* in_sizes, int n_in,
                              void* d_out, int out_size, void* d_ws, size_t ws_size,
                              hipStream_t stream) {
    const float* x = (const float*)d_in[0];
    const float* y = (const float*)d_in[1];
    const float* t = (const float*)d_in[8];
    const float* l = (const float*)d_in[9];
    const float* a = (const float*)d_in[10];

    float* u1out = (float*)d_out;
    float* u2out = u1out + NPIX;

    // ws: rc(f32) + 7 packed half2 fields = 8 * 16.8 MB = 134 MB
    char* ws = (char*)d_ws;
    float*   rcp_ = (float*)ws;                              ws += (size_t)NPIX * 4;
    __half2* gaP  = (__half2*)ws;                            ws += (size_t)NPIX * 4;
    __half2* upA  = (__half2*)ws;                            ws += (size_t)NPIX * 4;
    __half2* upB  = (__half2*)ws;                            ws += (size_t)NPIX * 4;
    __half2* paA  = (__half2*)ws;                            ws += (size_t)NPIX * 4;
    __half2* pbA  = (__half2*)ws;                            ws += (size_t)NPIX * 4;
    __half2* paB  = (__half2*)ws;                            ws += (size_t)NPIX * 4;
    __half2* pbB  = (__half2*)ws;

    // FP1 (S fused): iterations 1-3 (p1..p3, u2..u4); computes ga/rc from
    // x,y in-prologue and writes them for FP2/FP3; p0 = 0, u1 in-register.
    fp_kernel<true, false><<<dim3(FBLK), dim3(FTHR), 0, stream>>>(
        gaP, rcp_, nullptr, nullptr, nullptr,
        upA, nullptr, nullptr, paA, pbA, t, l, a,
        x, y, gaP, rcp_);

    // FP2: iterations 4-6  (p4..p6, u5..u7)
    fp_kernel<false, false><<<dim3(FBLK), dim3(FTHR), 0, stream>>>(
        gaP, rcp_, upA, paA, pbA,
        upB, nullptr, nullptr, paB, pbB, t, l, a,
        nullptr, nullptr, nullptr, nullptr);

    // FP3: iterations 7-9 + final u(10) as fp32; dead p(9) store skipped
    fp_kernel<false, true><<<dim3(FBLK), dim3(FTHR), 0, stream>>>(
        gaP, rcp_, upB, paB, pbB,
        nullptr, u1out, u2out, nullptr, nullptr, t, l, a,
        nullptr, nullptr, nullptr, nullptr);
}

// Round 11
// 219.575 us; speedup vs baseline: 1.2539x; 1.0054x over previous
//
#include <hip/hip_runtime.h>
#include <hip/hip_fp16.h>

#define HH 256
#define WW 256
#define NB 64
#define NPIX (NB * HH * WW)      // 4,194,304 pixels
#define NF4  (NPIX / 4)          // 1,048,576 groups of 4
#define ROW4 (WW / 4)            // 64 groups per image row
#define EPSF 1e-12f
#define FTRH 8                   // output rows per tile
#define FTHR 512                 // 8 waves -> 8 rows per pass
#define TPI  (HH / FTRH)         // 32 tiles per image
#define FBLK (NB * TPI)          // 2048 blocks (FP kernel)
#define NIT  3                   // solver iterations fused per FP launch
#define NU   (FTRH + 2 * NIT)        // 14 LDS u rows
#define NPR  (FTRH + 2 * NIT - 1)    // 13 LDS p rows
// Round-3 structure (proven 226.8): shifting row ownership, fp16-packed LDS,
// 40 KB -> 4 blocks/CU, 32-VGPR class, 62% occupancy. This round fuses the
// S kernel into FP1 (round-10's win): ga/rc computed from x,y in-kernel.
// FP1's u-steps RECOMPUTE ga/rc from x,y (pure function of inputs -> no
// cross-block race on the freshly written ga/rc); own rows stored
// exactly-once for FP2/FP3, which are byte-identical to round 3.

__device__ __forceinline__ float4 ld4(const float* p, int f) {
    return ((const float4*)p)[f];
}
__device__ __forceinline__ void st4(float* p, int f, const float* v) {
    ((float4*)p)[f] = make_float4(v[0], v[1], v[2], v[3]);
}
// Packed-pair load: 4 pixels of a __half2 field (16B) -> two float[4]
__device__ __forceinline__ void ld8h(const __half2* p, int f, float* a, float* b) {
    float4 raw = ((const float4*)p)[f];
    const __half2* h = (const __half2*)&raw;
    #pragma unroll
    for (int k = 0; k < 4; ++k) {
        float2 v = __half22float2(h[k]);
        a[k] = v.x; b[k] = v.y;
    }
}
__device__ __forceinline__ void st8h(__half2* p, int f, const float* a, const float* b) {
    float4 raw;
    __half2* h = (__half2*)&raw;
    #pragma unroll
    for (int k = 0; k < 4; ++k) h[k] = __floats2half2_rn(a[k], b[k]);
    ((float4*)p)[f] = raw;
}
// Pack 4 px of two fields into 4 __half2 inside a float4 (for LDS 16B store)
__device__ __forceinline__ float4 pack4h2(const float* a, const float* b) {
    float4 raw;
    __half2* h = (__half2*)&raw;
    #pragma unroll
    for (int k = 0; k < 4; ++k) h[k] = __floats2half2_rn(a[k], b[k]);
    return raw;
}
__device__ __forceinline__ void unpack4h2(float4 raw, float* a, float* b) {
    const __half2* h = (const __half2*)&raw;
    #pragma unroll
    for (int k = 0; k < 4; ++k) {
        float2 v = __half22float2(h[k]);
        a[k] = v.x; b[k] = v.y;
    }
}
// Extract (a,b) floats from a raw 32-bit half2 word.
__device__ __forceinline__ void h2w(unsigned int w, float& a, float& b) {
    __half2 h = *(__half2*)&w;
    float2 v = __half22float2(h);
    a = v.x; b = v.y;
}

// TV-L1 thresholding step, branch-free:
//   v = med3(-rho/grad, -l_t, l_t) * g   — agrees exactly with the 3-mask
// reference logic. grad >= EPSF so rcp is safe.
__device__ __forceinline__ void thresh(
    float gx, float gy, float rho, float grad, float l_t,
    float& v1, float& v2)
{
    float s = -rho * __builtin_amdgcn_rcpf(grad);
    float c = __builtin_amdgcn_fmed3f(s, -l_t, l_t);
    v1 = c * gx; v2 = c * gy;
}

// p-pair update at one pixel for one flow (approx sqrt/rcp: err ~2^-22,
// far below the fp16 quantization every state field already pays).
__device__ __forceinline__ void pupd(
    float pao, float pbo, float ux, float uy, float taut,
    float& pa, float& pb)
{
    float n2 = fmaf(ux, ux, fmaf(uy, uy, EPSF));
    float n  = __builtin_amdgcn_sqrtf(n2);
    float r  = __builtin_amdgcn_rcpf(fmaf(taut, n, 1.f));
    pa = fmaf(taut, ux, pao) * r;
    pb = fmaf(taut, uy, pbo) * r;
}

// Compute ga=(gx,gy) (fp16-quantized) and rc=y-x (fp32) for global row gr
// from x,y. Wave spans the full row: column neighbors via shuffles.
// Identical math to the original s_kernel.
__device__ __forceinline__ void garc_row(
    const float* __restrict__ xg, const float* __restrict__ yg,
    int f, int gr, int tc, float* gx, float* gy, float* rcv)
{
    float4 xc4 = ld4(xg, f), yc4 = ld4(yg, f);
    const float* xc = (const float*)&xc4;
    const float* yc = (const float*)&yc4;
    float4 a4, b4;                       // wave-uniform row branch
    if (gr == 0)           { a4 = ld4(xg, f + ROW4); b4 = xc4; }
    else if (gr == HH - 1) { a4 = xc4; b4 = ld4(xg, f - ROW4); }
    else                   { a4 = ld4(yg, f + ROW4); b4 = ld4(yg, f - ROW4); }
    const float* aa = (const float*)&a4;
    const float* bb = (const float*)&b4;
    float yl = __shfl_up(yc4.w, 1);      // lane 0 value unused (j==0)
    float yr = __shfl_down(yc4.x, 1);    // lane 63 value unused (j==WW-1)
    #pragma unroll
    for (int k = 0; k < 4; ++k) {
        int j = tc + k;
        float g;
        if (j == 0)            g = 0.5f * (xc[1] - xc[0]);
        else if (j == WW - 1)  g = 0.5f * (xc[3] - xc[2]);
        else {
            float ynext = (k < 3) ? yc[k + 1] : yr;
            float yprev = (k > 0) ? yc[k - 1] : yl;
            g = 0.5f * (ynext - yprev);
        }
        float gyv = 0.5f * (aa[k] - bb[k]);
        // quantize NOW so FP1's iterations match FP2/FP3's fp16 readback
        gx[k] = __half2float(__float2half_rn(g));
        gy[k] = __half2float(__float2half_rn(gyv));
        rcv[k] = yc[k] - xc[k];
    }
}

// ---------------------------------------------------------------------------
// FP: 3 fused solver iterations over an 8-row x 256-col tile with halo
// recompute, shifting row ownership (round-3 structure). One wave owns a
// full row per row-step; left/right px neighbors travel by lane shuffle.
//   sU  : (u1,u2) fp16x2, rows rel [-3, 10]. In-place u-update (same-px).
//   sPA : (p11,p21), sPB : (p12,p22), rows rel [-3, 9]. In-place p-update.
// P0: S fused — ga/rc computed from x,y (prologue seeds u(1); u-steps
// recompute; own rows stored exactly-once for FP2/FP3); p(k-1)=0.
// LAST: final u written fp32 to d_out, dead p store skipped.
// ---------------------------------------------------------------------------
template <bool P0, bool LAST>
__global__ __launch_bounds__(FTHR, 8) void fp_kernel(
    const __half2* __restrict__ ga, const float* __restrict__ rc,
    const __half2* __restrict__ upi,
    const __half2* __restrict__ pai, const __half2* __restrict__ pbi,
    __half2* __restrict__ upo,
    float* __restrict__ u1f, float* __restrict__ u2f,
    __half2* __restrict__ pao, __half2* __restrict__ pbo,
    const float* __restrict__ tp, const float* __restrict__ lp,
    const float* __restrict__ ap,
    const float* __restrict__ xg, const float* __restrict__ yg,
    __half2* __restrict__ gao, float* __restrict__ rco)
{
    __shared__ alignas(16) __half2 sU [NU ][WW];
    __shared__ alignas(16) __half2 sPA[NPR][WW];
    __shared__ alignas(16) __half2 sPB[NPR][WW];

    const float ts   = tp[0];
    const float l_t  = lp[0] * ts;
    const float taut = ap[0] / ts;

    const int t     = threadIdx.x;
    const int tile  = blockIdx.x;
    const int i0    = (tile & (TPI - 1)) * FTRH;   // tile top row
    const int base4 = (tile / TPI) * (HH * ROW4);  // batch offset, float4 units

    const int tr  = t >> 6;       // wave index 0..7 = row within pass
    const int tcg = t & 63;       // lane
    const int tc  = tcg * 4;

    // ---- prologue: u(k) -> sU rows [-3, 10] ----
    for (int rr = tr - NIT; rr <= FTRH + NIT - 1; rr += FTRH) {
        int gr = i0 + rr;
        float4* dst = (float4*)&sU[rr + NIT][tc];
        if (gr >= 0 && gr < HH) {
            int f = base4 + gr * ROW4 + tcg;
            if (P0) {
                // fused s_kernel: ga/rc from x,y; u(1) = thresh (div(p0)=0)
                float gx[4], gy[4], rcv[4];
                garc_row(xg, yg, f, gr, tc, gx, gy, rcv);
                float v1[4], v2[4];
                #pragma unroll
                for (int k = 0; k < 4; ++k) {
                    float grad = fmaf(gx[k], gx[k], fmaf(gy[k], gy[k], EPSF));
                    float rho  = rcv[k] + EPSF;           // u = 0
                    thresh(gx[k], gy[k], rho, grad, l_t, v1[k], v2[k]);
                }
                *dst = pack4h2(v1, v2);
                // store ga/rc for FP2/FP3 (own rows only: exactly-once)
                if (rr >= 0 && rr < FTRH) {
                    st8h(gao, f, gx, gy);      // values already fp16-exact
                    st4(rco, f, rcv);
                }
            } else {
                *dst = ((const float4*)upi)[f];           // raw fp16 copy
            }
        } else {
            *dst = make_float4(0.f, 0.f, 0.f, 0.f);
        }
    }
    __syncthreads();

    #pragma unroll
    for (int m = 0; m < NIT; ++m) {
        // ===== p-step m: p(k+m) at rows [-(NIT-m), FTRH-1+(NIT-1-m)] =====
        const int plo = -(NIT - m);
        const int phi = FTRH - 1 + (NIT - 1 - m);
        for (int rr = tr + plo; rr <= phi; rr += FTRH) {
            int gr = i0 + rr;
            int li = rr + NIT;
            if (gr >= 0 && gr < HH) {
                float4 rawU = *(const float4*)&sU[li][tc];
                float u1c[4], u2c[4];
                unpack4h2(rawU, u1c, u2c);
                float u1d[4] = {0,0,0,0}, u2d[4] = {0,0,0,0};
                bool hasDn = (gr < HH - 1);
                if (hasDn) unpack4h2(*(const float4*)&sU[li + 1][tc], u1d, u2d);
                // right-neighbor px from lane+1 (word 0 of its rawU)
                unsigned int w0 = ((const unsigned int*)&rawU)[0];
                unsigned int nb = __shfl_down((int)w0, 1);
                float u1r, u2r;  h2w(nb, u1r, u2r);   // lane 63 unused
                float c11[4], c12[4], c21[4], c22[4];
                if (m == 0) {
                    if (P0) {
                        #pragma unroll
                        for (int k = 0; k < 4; ++k) { c11[k]=c12[k]=c21[k]=c22[k]=0.f; }
                    } else {
                        int f = base4 + gr * ROW4 + tcg;
                        ld8h(pai, f, c11, c12);
                        ld8h(pbi, f, c21, c22);
                    }
                } else {
                    unpack4h2(*(const float4*)&sPA[li][tc], c11, c21);
                    unpack4h2(*(const float4*)&sPB[li][tc], c12, c22);
                }
                float p11n[4], p12n[4], p21n[4], p22n[4];
                #pragma unroll
                for (int k = 0; k < 4; ++k) {
                    int j = tc + k;
                    float du1 = (k < 3) ? u1c[k + 1] : u1r;
                    float du2 = (k < 3) ? u2c[k + 1] : u2r;
                    float u1x = (j < WW - 1) ? du1 - u1c[k] : 0.f;
                    float u2x = (j < WW - 1) ? du2 - u2c[k] : 0.f;
                    float u1y = hasDn ? u1d[k] - u1c[k] : 0.f;
                    float u2y = hasDn ? u2d[k] - u2c[k] : 0.f;
                    pupd(c11[k], c12[k], u1x, u1y, taut, p11n[k], p12n[k]);
                    pupd(c21[k], c22[k], u2x, u2y, taut, p21n[k], p22n[k]);
                }
                *(float4*)&sPA[li][tc] = pack4h2(p11n, p21n);
                *(float4*)&sPB[li][tc] = pack4h2(p12n, p22n);
                if (m == NIT - 1 && !LAST && rr >= 0 && rr < FTRH) {
                    int f = base4 + gr * ROW4 + tcg;
                    st8h(pao, f, p11n, p12n);
                    st8h(pbo, f, p21n, p22n);
                }
            } else {
                *(float4*)&sPA[li][tc] = make_float4(0.f, 0.f, 0.f, 0.f);
                *(float4*)&sPB[li][tc] = make_float4(0.f, 0.f, 0.f, 0.f);
            }
        }
        __syncthreads();

        // ===== u-step m: u(k+m+1) at rows [-(NIT-1-m), FTRH-1+(NIT-1-m)] =====
        const int ulo = -(NIT - 1 - m);
        const int uhi = FTRH - 1 + (NIT - 1 - m);
        for (int rr = tr + ulo; rr <= uhi; rr += FTRH) {
            int gr = i0 + rr;
            int li = rr + NIT;
            if (gr < 0 || gr >= HH) continue;     // out-of-image rows stay 0
            int f = base4 + gr * ROW4 + tcg;
            float gx[4], gy[4], rcv[4];
            if (P0) {
                // recompute from x,y: pure function of inputs -> no race
                // with this launch's own ga/rc stores (L2-resident reads)
                garc_row(xg, yg, f, gr, tc, gx, gy, rcv);
            } else {
                ld8h(ga, f, gx, gy);              // halo re-reads hit L1/L2
                float4 rc4 = ld4(rc, f);
                rcv[0]=rc4.x; rcv[1]=rc4.y; rcv[2]=rc4.z; rcv[3]=rc4.w;
            }
            float u1c[4], u2c[4];
            unpack4h2(*(const float4*)&sU[li][tc], u1c, u2c);
            float4 rawA = *(const float4*)&sPA[li][tc];
            float p11[4], p21[4], p12[4], p22[4], q12[4], q22[4];
            unpack4h2(rawA, p11, p21);
            unpack4h2(*(const float4*)&sPB[li][tc], p12, p22);
            unpack4h2(*(const float4*)&sPB[li - 1][tc], q12, q22);   // row r-1
            // left-neighbor px from lane-1 (word 3 of its rawA)
            unsigned int w3 = ((const unsigned int*)&rawA)[3];
            unsigned int lw = __shfl_up((int)w3, 1);
            float l11, l21;  h2w(lw, l11, l21);
            if (tcg == 0) { l11 = 0.f; l21 = 0.f; }   // j==0 boundary
            bool hasDn = (gr < HH - 1);
            float u1n[4], u2n[4];
            #pragma unroll
            for (int k = 0; k < 4; ++k) {
                int j = tc + k;
                float t11  = (j < WW - 1) ? p11[k] : 0.f;
                float t21  = (j < WW - 1) ? p21[k] : 0.f;
                float l11k = (k == 0) ? l11 : p11[k - 1];
                float l21k = (k == 0) ? l21 : p21[k - 1];
                float t12  = hasDn ? p12[k] : 0.f;
                float t22  = hasDn ? p22[k] : 0.f;
                float div1 = (t11 - l11k) + (t12 - q12[k]);
                float div2 = (t21 - l21k) + (t22 - q22[k]);

                float grad = fmaf(gx[k], gx[k], fmaf(gy[k], gy[k], EPSF));
                float rho  = rcv[k] + gx[k]*u1c[k] + gy[k]*u2c[k] + EPSF;
                float v1, v2;
                thresh(gx[k], gy[k], rho, grad, l_t, v1, v2);
                u1n[k] = v1 + u1c[k] + ts * div1;
                u2n[k] = v2 + u2c[k] + ts * div2;
            }
            if (m == NIT - 1) {
                if (LAST) { st4(u1f, f, u1n); st4(u2f, f, u2n); }
                else      { st8h(upo, f, u1n, u2n); }
            } else {
                *(float4*)&sU[li][tc] = pack4h2(u1n, u2n);   // same-px in-place
            }
        }
        if (m < NIT - 1) __syncthreads();
    }
}

// ---------------------------------------------------------------------------
extern "C" void kernel_launch(void* const* d_in, const int* in_sizes, int n_in,
                              void* d_out, int out_size, void* d_ws, size_t ws_size,
                              hipStream_t stream) {
    const float* x = (const float*)d_in[0];
    const float* y = (const float*)d_in[1];
    const float* t = (const float*)d_in[8];
    const float* l = (const float*)d_in[9];
    const float* a = (const float*)d_in[10];

    float* u1out = (float*)d_out;
    float* u2out = u1out + NPIX;

    // ws: rc(f32) + 7 packed half2 fields = 8 * 16.8 MB = 134 MB
    char* ws = (char*)d_ws;
    float*   rcp_ = (float*)ws;                              ws += (size_t)NPIX * 4;
    __half2* gaP  = (__half2*)ws;                            ws += (size_t)NPIX * 4;
    __half2* upA  = (__half2*)ws;                            ws += (size_t)NPIX * 4;
    __half2* upB  = (__half2*)ws;                            ws += (size_t)NPIX * 4;
    __half2* paA  = (__half2*)ws;                            ws += (size_t)NPIX * 4;
    __half2* pbA  = (__half2*)ws;                            ws += (size_t)NPIX * 4;
    __half2* paB  = (__half2*)ws;                            ws += (size_t)NPIX * 4;
    __half2* pbB  = (__half2*)ws;

    // FP1 (S fused): iterations 1-3 (p1..p3, u2..u4); ga/rc computed from
    // x,y in-kernel and stored for FP2/FP3; p0 = 0, u1 in-register.
    fp_kernel<true, false><<<dim3(FBLK), dim3(FTHR), 0, stream>>>(
        gaP, rcp_, nullptr, nullptr, nullptr,
        upA, nullptr, nullptr, paA, pbA, t, l, a,
        x, y, gaP, rcp_);

    // FP2: iterations 4-6  (p4..p6, u5..u7)
    fp_kernel<false, false><<<dim3(FBLK), dim3(FTHR), 0, stream>>>(
        gaP, rcp_, upA, paA, pbA,
        upB, nullptr, nullptr, paB, pbB, t, l, a,
        nullptr, nullptr, nullptr, nullptr);

    // FP3: iterations 7-9 + final u(10) as fp32; dead p(9) store skipped
    fp_kernel<false, true><<<dim3(FBLK), dim3(FTHR), 0, stream>>>(
        gaP, rcp_, upB, paB, pbB,
        nullptr, u1out, u2out, nullptr, nullptr, t, l, a,
        nullptr, nullptr, nullptr, nullptr);
}